// Round 1
// baseline (1128.717 us; speedup 1.0000x reference)
//
#include <hip/hip_runtime.h>
#include <cmath>
#include <climits>

#define DEV __device__ __forceinline__

constexpr int NN  = 50000;    // real nodes
constexpr int NE  = 400000;   // regular edges
constexpr int NV  = NN + 1;   // + virtual node
constexpr int IND = 256;      // input dim
constexpr int HD  = 128;      // hidden dim
constexpr int NHC = 256;      // heads * hidden = GEMM N

DEV float lrelu(float x) { return x > 0.f ? x : 0.2f * x; }
DEV int   fkey(float f)  { int b = __float_as_int(f); return b >= 0 ? b : b ^ 0x7FFFFFFF; }
DEV float funkey(int k)  { return __int_as_float(k >= 0 ? k : k ^ 0x7FFFFFFF); }
DEV float gelu(float x)  { return x * 0.5f * (1.f + erff(x * 0.70710678118654752f)); }

// merge two online-softmax states (m,d)
DEV void md_merge(float& m, float& d, float m2, float d2) {
    float M = fmaxf(m, m2);
    if (M == -INFINITY) { m = M; d = 0.f; return; }
    d = d * __expf(m - M) + d2 * __expf(m2 - M);
    m = M;
}

// ---------------- setup kernels ----------------

__global__ __launch_bounds__(256) void zero_init(int* counts, float* colsum) {
    int t = blockIdx.x * 256 + threadIdx.x;
    if (t < NN)  counts[t] = 0;
    if (t < 256) colsum[t] = 0.f;
}

// copy X -> Xv rows [0,NN), accumulate column partial sums
__global__ __launch_bounds__(256) void vnode_partial(const float* __restrict__ X,
                                                     float* __restrict__ Xv,
                                                     float* __restrict__ colsum) {
    int j  = threadIdx.x;
    int r0 = blockIdx.x * 64;
    int re = min(r0 + 64, NN);
    float s = 0.f;
    for (int r = r0; r < re; ++r) {
        float v = X[(size_t)r * IND + j];
        Xv[(size_t)r * IND + j] = v;
        s += v;
    }
    atomicAdd(&colsum[j], s);
}

__global__ __launch_bounds__(256) void vnode_finalize(const float* __restrict__ colsum,
                                                      float* __restrict__ Xv) {
    int j = threadIdx.x;
    Xv[(size_t)NN * IND + j] = colsum[j] * (1.0f / NN);
}

__global__ __launch_bounds__(256) void count_kernel(const int* __restrict__ ei, int* __restrict__ counts) {
    int e = blockIdx.x * 256 + threadIdx.x;
    if (e < NE) atomicAdd(&counts[ei[NE + e]], 1);
}

__global__ __launch_bounds__(1024) void scan_kernel(const int* __restrict__ counts,
                                                    int* __restrict__ row_start,
                                                    int* __restrict__ cursor) {
    __shared__ int part[1024];
    int t = threadIdx.x;
    const int CH = (NN + 1023) / 1024; // 49
    int lo = t * CH, hi = min(lo + CH, NN);
    int s = 0;
    for (int i = lo; i < hi; ++i) s += counts[i];
    part[t] = s;
    __syncthreads();
    for (int off = 1; off < 1024; off <<= 1) {
        int v = part[t];
        int u = (t >= off) ? part[t - off] : 0;
        __syncthreads();
        part[t] = v + u;
        __syncthreads();
    }
    int excl = (t == 0) ? 0 : part[t - 1];
    for (int i = lo; i < hi; ++i) {
        row_start[i] = excl;
        cursor[i]    = excl;
        excl += counts[i];
    }
    if (t == 1023) row_start[NN] = part[1023];
}

__global__ __launch_bounds__(256) void fill_kernel(const int* __restrict__ ei,
                                                   int* __restrict__ cursor,
                                                   int* __restrict__ csr) {
    int e = blockIdx.x * 256 + threadIdx.x;
    if (e < NE) {
        int d   = ei[NE + e];
        int pos = atomicAdd(&cursor[d], 1);
        csr[pos] = ei[e];
    }
}

// ---------------- per-layer kernels ----------------

// H[nrows][256] = A[nrows][K] @ B[K][256]; one wave per block, 16 rows x 256 cols
template <int K>
__global__ __launch_bounds__(64) void gemm_nodes(const float* __restrict__ A,
                                                 const float* __restrict__ B,
                                                 float* __restrict__ H, int nrows) {
    __shared__ float As[16][K];
    int r0   = blockIdx.x * 16;
    int lane = threadIdx.x;
    int rows_here = min(16, nrows - r0);
    const float4* A4  = reinterpret_cast<const float4*>(A + (size_t)r0 * K);
    float4*       As4 = reinterpret_cast<float4*>(&As[0][0]);
    for (int i = lane; i < rows_here * K / 4; i += 64) As4[i] = A4[i];
    __syncthreads();

    float acc[16][4] = {};
    for (int k = 0; k < K; k += 4) {
        float bv[4][4];
#pragma unroll
        for (int kk = 0; kk < 4; ++kk)
#pragma unroll
            for (int c = 0; c < 4; ++c)
                bv[kk][c] = B[(k + kk) * NHC + (c << 6) + lane];
#pragma unroll
        for (int t = 0; t < 16; ++t) {
            float4 a = *reinterpret_cast<const float4*>(&As[t][k]);
#pragma unroll
            for (int kk = 0; kk < 4; ++kk) {
                float av = (&a.x)[kk];
#pragma unroll
                for (int c = 0; c < 4; ++c) acc[t][c] += av * bv[kk][c];
            }
        }
    }
    for (int t = 0; t < rows_here; ++t)
#pragma unroll
        for (int c = 0; c < 4; ++c)
            H[(size_t)(r0 + t) * NHC + (c << 6) + lane] = acc[t][c];
}

// alpha_s[n][h], alpha_d[n][h]; one wave per node
__global__ __launch_bounds__(256) void alpha_kernel(const float* __restrict__ H,
                                                    const float* __restrict__ a_s,
                                                    const float* __restrict__ a_d,
                                                    float* __restrict__ as_,
                                                    float* __restrict__ ad_) {
    int wave = threadIdx.x >> 6, lane = threadIdx.x & 63;
    int node = blockIdx.x * 4 + wave;
    if (node >= NV) return;
    const float* h = H + (size_t)node * NHC;
    float v0 = h[lane], v1 = h[lane + 64], v2 = h[lane + 128], v3 = h[lane + 192];
    float s0 = v0 * a_s[lane] + v1 * a_s[lane + 64];
    float s1 = v2 * a_s[lane + 128] + v3 * a_s[lane + 192];
    float d0 = v0 * a_d[lane] + v1 * a_d[lane + 64];
    float d1 = v2 * a_d[lane + 128] + v3 * a_d[lane + 192];
    for (int off = 32; off; off >>= 1) {
        s0 += __shfl_xor(s0, off); s1 += __shfl_xor(s1, off);
        d0 += __shfl_xor(d0, off); d1 += __shfl_xor(d1, off);
    }
    if (lane == 0) {
        as_[node * 2] = s0; as_[node * 2 + 1] = s1;
        ad_[node * 2] = d0; ad_[node * 2 + 1] = d1;
    }
}

__global__ __launch_bounds__(256) void init_virt(int* vm, float* vden, float* vacc) {
    int t = threadIdx.x;
    vacc[t] = 0.f;
    if (t < 2) { vm[t] = INT_MIN; vden[t] = 0.f; }
}

// max over all NV in-edges of the virtual node
__global__ __launch_bounds__(256) void vmax_kernel(const float* __restrict__ as_,
                                                   const float* __restrict__ ad_,
                                                   int* __restrict__ vm) {
    float ad0 = ad_[NN * 2], ad1 = ad_[NN * 2 + 1];
    float m0 = -INFINITY, m1 = -INFINITY;
    for (int r = blockIdx.x * 256 + threadIdx.x; r < NV; r += gridDim.x * 256) {
        m0 = fmaxf(m0, lrelu(as_[r * 2] + ad0));
        m1 = fmaxf(m1, lrelu(as_[r * 2 + 1] + ad1));
    }
    for (int off = 32; off; off >>= 1) {
        m0 = fmaxf(m0, __shfl_xor(m0, off));
        m1 = fmaxf(m1, __shfl_xor(m1, off));
    }
    __shared__ float lm0[4], lm1[4];
    int wave = threadIdx.x >> 6, lane = threadIdx.x & 63;
    if (lane == 0) { lm0[wave] = m0; lm1[wave] = m1; }
    __syncthreads();
    if (threadIdx.x == 0) {
        m0 = fmaxf(fmaxf(lm0[0], lm0[1]), fmaxf(lm0[2], lm0[3]));
        m1 = fmaxf(fmaxf(lm1[0], lm1[1]), fmaxf(lm1[2], lm1[3]));
        atomicMax(&vm[0], fkey(m0));
        atomicMax(&vm[1], fkey(m1));
    }
}

// weighted sum over all NV rows into vacc[256], denom into vden[2]
__global__ __launch_bounds__(256) void vsum_kernel(const float* __restrict__ as_,
                                                   const float* __restrict__ ad_,
                                                   const float* __restrict__ H,
                                                   const int* __restrict__ vm,
                                                   float* __restrict__ vden,
                                                   float* __restrict__ vacc) {
    int j = threadIdx.x;
    int h = j >> 7;
    float adh = ad_[NN * 2 + h];
    float mh  = funkey(vm[h]);
    int r0 = blockIdx.x * 64, re = min(r0 + 64, NV);
    float acc = 0.f, dsum = 0.f;
    for (int r = r0; r < re; ++r) {
        float e = lrelu(as_[r * 2 + h] + adh);
        float w = __expf(e - mh);
        acc += w * H[(size_t)r * NHC + j];
        dsum += w;
    }
    atomicAdd(&vacc[j], acc);
    if ((j & 127) == 0) atomicAdd(&vden[h], dsum);
}

// virtual-node epilogue: normalize, mean heads, bias, LN, gelu
__global__ __launch_bounds__(256) void vpost_kernel(const float* __restrict__ vacc,
                                                    const float* __restrict__ vden,
                                                    const float* __restrict__ b,
                                                    const float* __restrict__ g,
                                                    const float* __restrict__ be,
                                                    float* __restrict__ hn) {
    __shared__ float o[256];
    __shared__ float red[256];
    int j = threadIdx.x, h = j >> 7;
    o[j] = vacc[j] / (vden[h] + 1e-16f);
    __syncthreads();
    float y = 0.f;
    if (j < HD) y = 0.5f * (o[j] + o[j + HD]) + b[j];
    red[j] = (j < HD) ? y : 0.f;
    __syncthreads();
    for (int s = 64; s; s >>= 1) { if (j < s) red[j] += red[j + s]; __syncthreads(); }
    float mu = red[0] * (1.f / HD);
    __syncthreads();
    float c = (j < HD) ? (y - mu) : 0.f;
    red[j] = c * c;
    __syncthreads();
    for (int s = 64; s; s >>= 1) { if (j < s) red[j] += red[j + s]; __syncthreads(); }
    float var = red[0] * (1.f / HD);
    if (j < HD) {
        float xn = (y - mu) * rsqrtf(var + 1e-5f) * g[j] + be[j];
        hn[(size_t)NN * HD + j] = gelu(xn);
    }
}

// regular nodes: one wave per dst node; softmax over {csr edges, virtual, self};
// aggregate + mean-heads + bias + LN + gelu fused
__global__ __launch_bounds__(256) void node_kernel(const int* __restrict__ row_start,
                                                   const int* __restrict__ csr,
                                                   const float* __restrict__ as_,
                                                   const float* __restrict__ ad_,
                                                   const float* __restrict__ H,
                                                   const float* __restrict__ b,
                                                   const float* __restrict__ g,
                                                   const float* __restrict__ be,
                                                   float* __restrict__ hn) {
    int wave = threadIdx.x >> 6, lane = threadIdx.x & 63;
    int i = blockIdx.x * 4 + wave;
    if (i >= NN) return;
    int rs = row_start[i], cnt = row_start[i + 1] - rs;
    int tot = cnt + 2; // + virtual, + self
    float ad0 = ad_[i * 2], ad1 = ad_[i * 2 + 1];

    // phase A: online softmax stats per head
    float m0 = -INFINITY, d0 = 0.f, m1 = -INFINITY, d1 = 0.f;
    for (int idx = lane; idx < tot; idx += 64) {
        int src = idx < cnt ? csr[rs + idx] : (idx == cnt ? NN : i);
        float e0 = lrelu(as_[src * 2] + ad0);
        float e1 = lrelu(as_[src * 2 + 1] + ad1);
        md_merge(m0, d0, e0, 1.f);
        md_merge(m1, d1, e1, 1.f);
    }
    for (int off = 32; off; off >>= 1) {
        float mm0 = __shfl_xor(m0, off), dd0 = __shfl_xor(d0, off);
        float mm1 = __shfl_xor(m1, off), dd1 = __shfl_xor(d1, off);
        md_merge(m0, d0, mm0, dd0);
        md_merge(m1, d1, mm1, dd1);
    }
    float r0 = 1.f / (d0 + 1e-16f), r1 = 1.f / (d1 + 1e-16f);

    // phase B: weighted aggregation; lane l holds cols l, l+64, l+128, l+192
    float a0 = 0.f, a1 = 0.f, a2 = 0.f, a3 = 0.f;
    for (int jj = 0; jj < tot; ++jj) {
        int src = jj < cnt ? csr[rs + jj] : (jj == cnt ? NN : i);
        float e0 = lrelu(as_[src * 2] + ad0);
        float e1 = lrelu(as_[src * 2 + 1] + ad1);
        float w0 = __expf(e0 - m0) * r0;
        float w1 = __expf(e1 - m1) * r1;
        const float* hr = H + (size_t)src * NHC;
        a0 += w0 * hr[lane];
        a1 += w0 * hr[lane + 64];
        a2 += w1 * hr[lane + 128];
        a3 += w1 * hr[lane + 192];
    }

    // epilogue: mean over heads + bias
    float ya = 0.5f * (a0 + a2) + b[lane];
    float yb = 0.5f * (a1 + a3) + b[lane + 64];
    // LN over 128 (2 values per lane)
    float s = ya + yb;
    for (int off = 32; off; off >>= 1) s += __shfl_xor(s, off);
    float mu = s * (1.f / HD);
    float ca = ya - mu, cb = yb - mu;
    float v = ca * ca + cb * cb;
    for (int off = 32; off; off >>= 1) v += __shfl_xor(v, off);
    float rstd = rsqrtf(v * (1.f / HD) + 1e-5f);
    float xa = ca * rstd * g[lane] + be[lane];
    float xb = cb * rstd * g[lane + 64] + be[lane + 64];
    hn[(size_t)i * HD + lane]      = gelu(xa);
    hn[(size_t)i * HD + 64 + lane] = gelu(xb);
}

// out[NN][64] = h[NN][128] @ Wout[128][64] + bout
__global__ __launch_bounds__(256) void out_gemm(const float* __restrict__ A,
                                                const float* __restrict__ W,
                                                const float* __restrict__ bout,
                                                float* __restrict__ out) {
    int wave = threadIdx.x >> 6, lane = threadIdx.x & 63;
    int r = blockIdx.x * 4 + wave;
    if (r >= NN) return;
    const float* a = A + (size_t)r * HD;
    float acc = 0.f;
#pragma unroll 8
    for (int k = 0; k < HD; ++k) acc += a[k] * W[k * 64 + lane];
    out[(size_t)r * 64 + lane] = acc + bout[lane];
}

// ---------------- launcher ----------------

extern "C" void kernel_launch(void* const* d_in, const int* in_sizes, int n_in,
                              void* d_out, int out_size, void* d_ws, size_t ws_size,
                              hipStream_t stream) {
    (void)in_sizes; (void)n_in; (void)out_size; (void)ws_size;

    const float* X  = (const float*)d_in[0];
    const int*   ei = (const int*)d_in[1];
    const float* W[3]  = {(const float*)d_in[3],  (const float*)d_in[9],  (const float*)d_in[15]};
    const float* Asp[3] = {(const float*)d_in[4],  (const float*)d_in[10], (const float*)d_in[16]};
    const float* Adp[3] = {(const float*)d_in[5],  (const float*)d_in[11], (const float*)d_in[17]};
    const float* Bb[3] = {(const float*)d_in[6],  (const float*)d_in[12], (const float*)d_in[18]};
    const float* Gg[3] = {(const float*)d_in[7],  (const float*)d_in[13], (const float*)d_in[19]};
    const float* Be[3] = {(const float*)d_in[8],  (const float*)d_in[14], (const float*)d_in[20]};
    const float* Wout = (const float*)d_in[21];
    const float* bout = (const float*)d_in[22];
    float* out = (float*)d_out;

    uintptr_t base = (uintptr_t)d_ws;
    auto take = [&](size_t bytes) {
        uintptr_t p = base;
        base += (bytes + 255) & ~(size_t)255;
        return p;
    };
    float* Xv     = (float*)take((size_t)NV * IND * 4);
    float* Hbuf   = (float*)take((size_t)NV * NHC * 4);
    float* hA     = (float*)take((size_t)NV * HD * 4);
    float* as_    = (float*)take((size_t)NV * 2 * 4);
    float* ad_    = (float*)take((size_t)NV * 2 * 4);
    float* colsum = (float*)take(256 * 4);
    int*   counts = (int*)take((size_t)NN * 4);
    int*   rowst  = (int*)take((size_t)(NN + 1) * 4);
    int*   cursor = (int*)take((size_t)NN * 4);
    int*   csr    = (int*)take((size_t)NE * 4);
    int*   vm     = (int*)take(2 * 4);
    float* vden   = (float*)take(2 * 4);
    float* vacc   = (float*)take(256 * 4);
    float* hB     = Xv; // alias: Xv is dead after the layer-0 GEMM

    // setup
    zero_init<<<196, 256, 0, stream>>>(counts, colsum);
    vnode_partial<<<(NN + 63) / 64, 256, 0, stream>>>(X, Xv, colsum);
    vnode_finalize<<<1, 256, 0, stream>>>(colsum, Xv);
    count_kernel<<<(NE + 255) / 256, 256, 0, stream>>>(ei, counts);
    scan_kernel<<<1, 1024, 0, stream>>>(counts, rowst, cursor);
    fill_kernel<<<(NE + 255) / 256, 256, 0, stream>>>(ei, cursor, csr);

    const float* hin = Xv;
    float* houts[3] = {hA, hB, hA};
    for (int li = 0; li < 3; ++li) {
        if (li == 0)
            gemm_nodes<IND><<<(NV + 15) / 16, 64, 0, stream>>>(hin, W[li], Hbuf, NV);
        else
            gemm_nodes<HD><<<(NV + 15) / 16, 64, 0, stream>>>(hin, W[li], Hbuf, NV);
        alpha_kernel<<<(NV + 3) / 4, 256, 0, stream>>>(Hbuf, Asp[li], Adp[li], as_, ad_);
        init_virt<<<1, 256, 0, stream>>>(vm, vden, vacc);
        vmax_kernel<<<128, 256, 0, stream>>>(as_, ad_, vm);
        vsum_kernel<<<(NV + 63) / 64, 256, 0, stream>>>(as_, ad_, Hbuf, vm, vden, vacc);
        vpost_kernel<<<1, 256, 0, stream>>>(vacc, vden, Bb[li], Gg[li], Be[li], houts[li]);
        node_kernel<<<(NN + 3) / 4, 256, 0, stream>>>(rowst, csr, as_, ad_, Hbuf,
                                                      Bb[li], Gg[li], Be[li], houts[li]);
        hin = houts[li];
    }
    out_gemm<<<(NN + 3) / 4, 256, 0, stream>>>(hin, Wout, bout, out);
}

// Round 2
// 912.874 us; speedup vs baseline: 1.2364x; 1.2364x over previous
//
#include <hip/hip_runtime.h>
#include <cmath>
#include <climits>

#define DEV __device__ __forceinline__

constexpr int NN  = 50000;    // real nodes
constexpr int NE  = 400000;   // regular edges
constexpr int NV  = NN + 1;   // + virtual node
constexpr int IND = 256;      // input dim
constexpr int HD  = 128;      // hidden dim
constexpr int NHC = 256;      // heads * hidden = GEMM N

typedef short short8 __attribute__((ext_vector_type(8)));
typedef float f32x4  __attribute__((ext_vector_type(4)));

DEV float lrelu(float x) { return x > 0.f ? x : 0.2f * x; }
DEV int   fkey(float f)  { int b = __float_as_int(f); return b >= 0 ? b : b ^ 0x7FFFFFFF; }
DEV float funkey(int k)  { return __int_as_float(k >= 0 ? k : k ^ 0x7FFFFFFF); }
DEV float gelu(float x)  { return x * 0.5f * (1.f + erff(x * 0.70710678118654752f)); }
// bf16 storage as ushort; RNE convert
DEV ushort f2bf(float f) { uint u = __float_as_uint(f); return (ushort)((u + 0x7FFFu + ((u >> 16) & 1u)) >> 16); }
DEV float  bf2f(ushort h) { return __uint_as_float((uint)h << 16); }

// merge two online-softmax states (m,d)
DEV void md_merge(float& m, float& d, float m2, float d2) {
    float M = fmaxf(m, m2);
    if (M == -INFINITY) { m = M; d = 0.f; return; }
    d = d * __expf(m - M) + d2 * __expf(m2 - M);
    m = M;
}

// ---------------- setup kernels ----------------

__global__ __launch_bounds__(256) void zero_init(int* counts, float* colsum) {
    int t = blockIdx.x * 256 + threadIdx.x;
    if (t < NN)  counts[t] = 0;
    if (t < 256) colsum[t] = 0.f;
}

// copy X -> Xv (bf16) rows [0,NN), accumulate column partial sums (fp32)
__global__ __launch_bounds__(256) void vnode_partial(const float* __restrict__ X,
                                                     ushort* __restrict__ Xv,
                                                     float* __restrict__ colsum) {
    int j  = threadIdx.x;
    int r0 = blockIdx.x * 64;
    int re = min(r0 + 64, NN);
    float s = 0.f;
    for (int r = r0; r < re; ++r) {
        float v = X[(size_t)r * IND + j];
        Xv[(size_t)r * IND + j] = f2bf(v);
        s += v;
    }
    atomicAdd(&colsum[j], s);
}

__global__ __launch_bounds__(256) void vnode_finalize(const float* __restrict__ colsum,
                                                      ushort* __restrict__ Xv) {
    int j = threadIdx.x;
    Xv[(size_t)NN * IND + j] = f2bf(colsum[j] * (1.0f / NN));
}

// W[K][256] fp32 -> Wt[256][K] bf16 (transposed for MFMA B-fragments)
__global__ __launch_bounds__(256) void conv_w(const float* __restrict__ W,
                                              ushort* __restrict__ Wt, int K) {
    int t = blockIdx.x * 256 + threadIdx.x;
    if (t < K * 256) {
        int k = t >> 8, n = t & 255;
        Wt[n * K + k] = f2bf(W[t]);
    }
}

__global__ __launch_bounds__(256) void count_kernel(const int* __restrict__ ei, int* __restrict__ counts) {
    int e = blockIdx.x * 256 + threadIdx.x;
    if (e < NE) atomicAdd(&counts[ei[NE + e]], 1);
}

__global__ __launch_bounds__(1024) void scan_kernel(const int* __restrict__ counts,
                                                    int* __restrict__ row_start,
                                                    int* __restrict__ cursor) {
    __shared__ int part[1024];
    int t = threadIdx.x;
    const int CH = (NN + 1023) / 1024; // 49
    int lo = t * CH, hi = min(lo + CH, NN);
    int s = 0;
    for (int i = lo; i < hi; ++i) s += counts[i];
    part[t] = s;
    __syncthreads();
    for (int off = 1; off < 1024; off <<= 1) {
        int v = part[t];
        int u = (t >= off) ? part[t - off] : 0;
        __syncthreads();
        part[t] = v + u;
        __syncthreads();
    }
    int excl = (t == 0) ? 0 : part[t - 1];
    for (int i = lo; i < hi; ++i) {
        row_start[i] = excl;
        cursor[i]    = excl;
        excl += counts[i];
    }
    if (t == 1023) row_start[NN] = part[1023];
}

__global__ __launch_bounds__(256) void fill_kernel(const int* __restrict__ ei,
                                                   int* __restrict__ cursor,
                                                   int* __restrict__ csr) {
    int e = blockIdx.x * 256 + threadIdx.x;
    if (e < NE) {
        int d   = ei[NE + e];
        int pos = atomicAdd(&cursor[d], 1);
        csr[pos] = ei[e];
    }
}

// ---------------- per-layer kernels ----------------

// H[NV][256](bf16) = A[NV][K](bf16) @ Wt[256][K]^T(bf16), fp32 acc via MFMA.
// Fused epilogue: as_[n][2], ad_[n][2] = sum_c H[n][c]*a_{s,d}[c].
// Block = 256 thr (4 waves); wave computes 16 rows x 256 cols; no LDS.
template <int K>
__global__ __launch_bounds__(256) void gemm_mfma(const ushort* __restrict__ A,
                                                 const ushort* __restrict__ Bt,
                                                 const float* __restrict__ a_s,
                                                 const float* __restrict__ a_d,
                                                 ushort* __restrict__ H,
                                                 float* __restrict__ as_,
                                                 float* __restrict__ ad_) {
    int wave = threadIdx.x >> 6, lane = threadIdx.x & 63;
    int r0   = blockIdx.x * 64 + wave * 16;
    int lrow = lane & 15, lk = lane >> 4;          // A: row=lrow, k-block=lk ; B: col=lrow
    int arow = min(r0 + lrow, NV - 1);
    const ushort* Ap = A  + (size_t)arow * K + lk * 8;
    const ushort* Bp = Bt + (size_t)lrow * K + lk * 8;

    f32x4 acc[16] = {};
    for (int k0 = 0; k0 < K; k0 += 32) {
        short8 af = *reinterpret_cast<const short8*>(Ap + k0);
#pragma unroll
        for (int f = 0; f < 16; ++f) {
            short8 bfr = *reinterpret_cast<const short8*>(Bp + k0 + (size_t)f * 16 * K);
            acc[f] = __builtin_amdgcn_mfma_f32_16x16x32_bf16(af, bfr, acc[f], 0, 0, 0);
        }
    }

    // C/D layout: col = 16f + lrow, row = r0 + lk*4 + r
    // store H (bf16)
#pragma unroll
    for (int f = 0; f < 16; ++f) {
        int c = 16 * f + lrow;
#pragma unroll
        for (int r = 0; r < 4; ++r) {
            int row = r0 + lk * 4 + r;
            if (row < NV) H[(size_t)row * NHC + c] = f2bf(acc[f][r]);
        }
    }

    // fused alpha: coefficient flat index == column index (a_src is [2][128] flat)
    float cs[16], cd[16];
#pragma unroll
    for (int f = 0; f < 16; ++f) {
        cs[f] = a_s[16 * f + lrow];
        cd[f] = a_d[16 * f + lrow];
    }
#pragma unroll
    for (int r = 0; r < 4; ++r) {
        float s0 = 0.f, s1 = 0.f, d0 = 0.f, d1 = 0.f;
#pragma unroll
        for (int f = 0; f < 8; ++f)  { s0 += acc[f][r] * cs[f]; d0 += acc[f][r] * cd[f]; }
#pragma unroll
        for (int f = 8; f < 16; ++f) { s1 += acc[f][r] * cs[f]; d1 += acc[f][r] * cd[f]; }
        // reduce across the 16 lrow lanes (lk bits untouched by xor<16)
        for (int off = 1; off < 16; off <<= 1) {
            s0 += __shfl_xor(s0, off); s1 += __shfl_xor(s1, off);
            d0 += __shfl_xor(d0, off); d1 += __shfl_xor(d1, off);
        }
        int row = r0 + lk * 4 + r;
        if (lrow == 0 && row < NV) {
            as_[row * 2] = s0; as_[row * 2 + 1] = s1;
            ad_[row * 2] = d0; ad_[row * 2 + 1] = d1;
        }
    }
}

__global__ __launch_bounds__(256) void init_virt(int* vm, float* vden, float* vacc) {
    int t = threadIdx.x;
    vacc[t] = 0.f;
    if (t < 2) { vm[t] = INT_MIN; vden[t] = 0.f; }
}

// max over all NV in-edges of the virtual node
__global__ __launch_bounds__(256) void vmax_kernel(const float* __restrict__ as_,
                                                   const float* __restrict__ ad_,
                                                   int* __restrict__ vm) {
    float ad0 = ad_[NN * 2], ad1 = ad_[NN * 2 + 1];
    float m0 = -INFINITY, m1 = -INFINITY;
    for (int r = blockIdx.x * 256 + threadIdx.x; r < NV; r += gridDim.x * 256) {
        m0 = fmaxf(m0, lrelu(as_[r * 2] + ad0));
        m1 = fmaxf(m1, lrelu(as_[r * 2 + 1] + ad1));
    }
    for (int off = 32; off; off >>= 1) {
        m0 = fmaxf(m0, __shfl_xor(m0, off));
        m1 = fmaxf(m1, __shfl_xor(m1, off));
    }
    __shared__ float lm0[4], lm1[4];
    int wave = threadIdx.x >> 6, lane = threadIdx.x & 63;
    if (lane == 0) { lm0[wave] = m0; lm1[wave] = m1; }
    __syncthreads();
    if (threadIdx.x == 0) {
        m0 = fmaxf(fmaxf(lm0[0], lm0[1]), fmaxf(lm0[2], lm0[3]));
        m1 = fmaxf(fmaxf(lm1[0], lm1[1]), fmaxf(lm1[2], lm1[3]));
        atomicMax(&vm[0], fkey(m0));
        atomicMax(&vm[1], fkey(m1));
    }
}

// weighted sum over all NV rows into vacc[256], denom into vden[2]
__global__ __launch_bounds__(256) void vsum_kernel(const float* __restrict__ as_,
                                                   const float* __restrict__ ad_,
                                                   const ushort* __restrict__ H,
                                                   const int* __restrict__ vm,
                                                   float* __restrict__ vden,
                                                   float* __restrict__ vacc) {
    int j = threadIdx.x;
    int h = j >> 7;
    float adh = ad_[NN * 2 + h];
    float mh  = funkey(vm[h]);
    int r0 = blockIdx.x * 64, re = min(r0 + 64, NV);
    float acc = 0.f, dsum = 0.f;
    for (int r = r0; r < re; ++r) {
        float e = lrelu(as_[r * 2 + h] + adh);
        float w = __expf(e - mh);
        acc += w * bf2f(H[(size_t)r * NHC + j]);
        dsum += w;
    }
    atomicAdd(&vacc[j], acc);
    if ((j & 127) == 0) atomicAdd(&vden[h], dsum);
}

// virtual-node epilogue: normalize, mean heads, bias, LN, gelu
__global__ __launch_bounds__(256) void vpost_kernel(const float* __restrict__ vacc,
                                                    const float* __restrict__ vden,
                                                    const float* __restrict__ b,
                                                    const float* __restrict__ g,
                                                    const float* __restrict__ be,
                                                    ushort* __restrict__ hn) {
    __shared__ float o[256];
    __shared__ float red[256];
    int j = threadIdx.x, h = j >> 7;
    o[j] = vacc[j] / (vden[h] + 1e-16f);
    __syncthreads();
    float y = 0.f;
    if (j < HD) y = 0.5f * (o[j] + o[j + HD]) + b[j];
    red[j] = (j < HD) ? y : 0.f;
    __syncthreads();
    for (int s = 64; s; s >>= 1) { if (j < s) red[j] += red[j + s]; __syncthreads(); }
    float mu = red[0] * (1.f / HD);
    __syncthreads();
    float c = (j < HD) ? (y - mu) : 0.f;
    red[j] = c * c;
    __syncthreads();
    for (int s = 64; s; s >>= 1) { if (j < s) red[j] += red[j + s]; __syncthreads(); }
    float var = red[0] * (1.f / HD);
    if (j < HD) {
        float xn = (y - mu) * rsqrtf(var + 1e-5f) * g[j] + be[j];
        hn[(size_t)NN * HD + j] = f2bf(gelu(xn));
    }
}

// regular nodes: one wave per dst node; softmax over {csr edges, virtual, self};
// aggregate + mean-heads + bias + LN + gelu fused
__global__ __launch_bounds__(256) void node_kernel(const int* __restrict__ row_start,
                                                   const int* __restrict__ csr,
                                                   const float* __restrict__ as_,
                                                   const float* __restrict__ ad_,
                                                   const ushort* __restrict__ H,
                                                   const float* __restrict__ b,
                                                   const float* __restrict__ g,
                                                   const float* __restrict__ be,
                                                   ushort* __restrict__ hn) {
    int wave = threadIdx.x >> 6, lane = threadIdx.x & 63;
    int i = blockIdx.x * 4 + wave;
    if (i >= NN) return;
    int rs = row_start[i], cnt = row_start[i + 1] - rs;
    int tot = cnt + 2; // + virtual, + self
    float ad0 = ad_[i * 2], ad1 = ad_[i * 2 + 1];

    // phase A: online softmax stats per head
    float m0 = -INFINITY, d0 = 0.f, m1 = -INFINITY, d1 = 0.f;
    for (int idx = lane; idx < tot; idx += 64) {
        int src = idx < cnt ? csr[rs + idx] : (idx == cnt ? NN : i);
        float e0 = lrelu(as_[src * 2] + ad0);
        float e1 = lrelu(as_[src * 2 + 1] + ad1);
        md_merge(m0, d0, e0, 1.f);
        md_merge(m1, d1, e1, 1.f);
    }
    for (int off = 32; off; off >>= 1) {
        float mm0 = __shfl_xor(m0, off), dd0 = __shfl_xor(d0, off);
        float mm1 = __shfl_xor(m1, off), dd1 = __shfl_xor(d1, off);
        md_merge(m0, d0, mm0, dd0);
        md_merge(m1, d1, mm1, dd1);
    }
    float r0 = 1.f / (d0 + 1e-16f), r1 = 1.f / (d1 + 1e-16f);

    // phase B: weighted aggregation; lane l holds cols l, l+64, l+128, l+192
    float a0 = 0.f, a1 = 0.f, a2 = 0.f, a3 = 0.f;
    for (int jj = 0; jj < tot; ++jj) {
        int src = jj < cnt ? csr[rs + jj] : (jj == cnt ? NN : i);
        float e0 = lrelu(as_[src * 2] + ad0);
        float e1 = lrelu(as_[src * 2 + 1] + ad1);
        float w0 = __expf(e0 - m0) * r0;
        float w1 = __expf(e1 - m1) * r1;
        const ushort* hr = H + (size_t)src * NHC;
        a0 += w0 * bf2f(hr[lane]);
        a1 += w0 * bf2f(hr[lane + 64]);
        a2 += w1 * bf2f(hr[lane + 128]);
        a3 += w1 * bf2f(hr[lane + 192]);
    }

    // epilogue: mean over heads + bias
    float ya = 0.5f * (a0 + a2) + b[lane];
    float yb = 0.5f * (a1 + a3) + b[lane + 64];
    // LN over 128 (2 values per lane)
    float s = ya + yb;
    for (int off = 32; off; off >>= 1) s += __shfl_xor(s, off);
    float mu = s * (1.f / HD);
    float ca = ya - mu, cb = yb - mu;
    float v = ca * ca + cb * cb;
    for (int off = 32; off; off >>= 1) v += __shfl_xor(v, off);
    float rstd = rsqrtf(v * (1.f / HD) + 1e-5f);
    float xa = ca * rstd * g[lane] + be[lane];
    float xb = cb * rstd * g[lane + 64] + be[lane + 64];
    hn[(size_t)i * HD + lane]      = f2bf(gelu(xa));
    hn[(size_t)i * HD + 64 + lane] = f2bf(gelu(xb));
}

// out[NN][64] = h[NN][128](bf16) @ Wout[128][64] + bout
__global__ __launch_bounds__(256) void out_gemm(const ushort* __restrict__ A,
                                                const float* __restrict__ W,
                                                const float* __restrict__ bout,
                                                float* __restrict__ out) {
    int wave = threadIdx.x >> 6, lane = threadIdx.x & 63;
    int r = blockIdx.x * 4 + wave;
    if (r >= NN) return;
    const ushort* a = A + (size_t)r * HD;
    float acc = 0.f;
#pragma unroll 8
    for (int k = 0; k < HD; ++k) acc += bf2f(a[k]) * W[k * 64 + lane];
    out[(size_t)r * 64 + lane] = acc + bout[lane];
}

// ---------------- launcher ----------------

extern "C" void kernel_launch(void* const* d_in, const int* in_sizes, int n_in,
                              void* d_out, int out_size, void* d_ws, size_t ws_size,
                              hipStream_t stream) {
    (void)in_sizes; (void)n_in; (void)out_size; (void)ws_size;

    const float* X  = (const float*)d_in[0];
    const int*   ei = (const int*)d_in[1];
    const float* W[3]   = {(const float*)d_in[3],  (const float*)d_in[9],  (const float*)d_in[15]};
    const float* Asp[3] = {(const float*)d_in[4],  (const float*)d_in[10], (const float*)d_in[16]};
    const float* Adp[3] = {(const float*)d_in[5],  (const float*)d_in[11], (const float*)d_in[17]};
    const float* Bb[3]  = {(const float*)d_in[6],  (const float*)d_in[12], (const float*)d_in[18]};
    const float* Gg[3]  = {(const float*)d_in[7],  (const float*)d_in[13], (const float*)d_in[19]};
    const float* Be[3]  = {(const float*)d_in[8],  (const float*)d_in[14], (const float*)d_in[20]};
    const float* Wout = (const float*)d_in[21];
    const float* bout = (const float*)d_in[22];
    float* out = (float*)d_out;

    uintptr_t base = (uintptr_t)d_ws;
    auto take = [&](size_t bytes) {
        uintptr_t p = base;
        base += (bytes + 255) & ~(size_t)255;
        return p;
    };
    ushort* Xv    = (ushort*)take((size_t)NV * IND * 2);
    ushort* Hbuf  = (ushort*)take((size_t)NV * NHC * 2);
    ushort* hA    = (ushort*)take((size_t)NV * HD * 2);
    ushort* hB    = (ushort*)take((size_t)NV * HD * 2);
    ushort* Wt0   = (ushort*)take((size_t)256 * IND * 2);
    ushort* Wt1   = (ushort*)take((size_t)256 * HD * 2);
    ushort* Wt2   = (ushort*)take((size_t)256 * HD * 2);
    float* as_    = (float*)take((size_t)NV * 2 * 4);
    float* ad_    = (float*)take((size_t)NV * 2 * 4);
    float* colsum = (float*)take(256 * 4);
    int*   counts = (int*)take((size_t)NN * 4);
    int*   rowst  = (int*)take((size_t)(NN + 1) * 4);
    int*   cursor = (int*)take((size_t)NN * 4);
    int*   csr    = (int*)take((size_t)NE * 4);
    int*   vm     = (int*)take(2 * 4);
    float* vden   = (float*)take(2 * 4);
    float* vacc   = (float*)take(256 * 4);
    ushort* Wt[3] = {Wt0, Wt1, Wt2};

    // setup
    zero_init<<<196, 256, 0, stream>>>(counts, colsum);
    vnode_partial<<<(NN + 63) / 64, 256, 0, stream>>>(X, Xv, colsum);
    vnode_finalize<<<1, 256, 0, stream>>>(colsum, Xv);
    conv_w<<<(IND * 256 + 255) / 256, 256, 0, stream>>>(W[0], Wt0, IND);
    conv_w<<<(HD  * 256 + 255) / 256, 256, 0, stream>>>(W[1], Wt1, HD);
    conv_w<<<(HD  * 256 + 255) / 256, 256, 0, stream>>>(W[2], Wt2, HD);
    count_kernel<<<(NE + 255) / 256, 256, 0, stream>>>(ei, counts);
    scan_kernel<<<1, 1024, 0, stream>>>(counts, rowst, cursor);
    fill_kernel<<<(NE + 255) / 256, 256, 0, stream>>>(ei, cursor, csr);

    const ushort* hin = Xv;
    ushort* houts[3] = {hA, hB, hA};
    for (int li = 0; li < 3; ++li) {
        if (li == 0)
            gemm_mfma<IND><<<(NV + 63) / 64, 256, 0, stream>>>(hin, Wt[li], Asp[li], Adp[li], Hbuf, as_, ad_);
        else
            gemm_mfma<HD><<<(NV + 63) / 64, 256, 0, stream>>>(hin, Wt[li], Asp[li], Adp[li], Hbuf, as_, ad_);
        init_virt<<<1, 256, 0, stream>>>(vm, vden, vacc);
        vmax_kernel<<<128, 256, 0, stream>>>(as_, ad_, vm);
        vsum_kernel<<<(NV + 63) / 64, 256, 0, stream>>>(as_, ad_, Hbuf, vm, vden, vacc);
        vpost_kernel<<<1, 256, 0, stream>>>(vacc, vden, Bb[li], Gg[li], Be[li], houts[li]);
        node_kernel<<<(NN + 3) / 4, 256, 0, stream>>>(rowst, csr, as_, ad_, Hbuf,
                                                      Bb[li], Gg[li], Be[li], houts[li]);
        hin = houts[li];
    }
    out_gemm<<<(NN + 3) / 4, 256, 0, stream>>>(hin, Wout, bout, out);
}

// Round 3
// 764.227 us; speedup vs baseline: 1.4769x; 1.1945x over previous
//
#include <hip/hip_runtime.h>
#include <cmath>
#include <climits>

#define DEV __device__ __forceinline__

constexpr int NN  = 50000;    // real nodes
constexpr int NE  = 400000;   // regular edges
constexpr int NV  = NN + 1;   // + virtual node
constexpr int IND = 256;      // input dim
constexpr int HD  = 128;      // hidden dim
constexpr int NHC = 256;      // heads * hidden = GEMM N
constexpr int NBLK = (NN + 255) / 256;  // 196 scan blocks

typedef short short8 __attribute__((ext_vector_type(8)));
typedef float f32x4  __attribute__((ext_vector_type(4)));

DEV float lrelu(float x) { return x > 0.f ? x : 0.2f * x; }
DEV int   fkey(float f)  { int b = __float_as_int(f); return b >= 0 ? b : b ^ 0x7FFFFFFF; }
DEV float funkey(int k)  { return __int_as_float(k >= 0 ? k : k ^ 0x7FFFFFFF); }
DEV float gelu(float x)  { return x * 0.5f * (1.f + erff(x * 0.70710678118654752f)); }
// bf16 storage as ushort; RNE convert
DEV ushort f2bf(float f) { uint u = __float_as_uint(f); return (ushort)((u + 0x7FFFu + ((u >> 16) & 1u)) >> 16); }
DEV float  bf2f(ushort h) { return __uint_as_float((uint)h << 16); }

// merge two online-softmax states (m,d)
DEV void md_merge(float& m, float& d, float m2, float d2) {
    float M = fmaxf(m, m2);
    if (M == -INFINITY) { m = M; d = 0.f; return; }
    d = d * __expf(m - M) + d2 * __expf(m2 - M);
    m = M;
}

// ---------------- setup kernels ----------------

__global__ __launch_bounds__(256) void zero_init(int* counts, float* colsum) {
    int t = blockIdx.x * 256 + threadIdx.x;
    if (t < NN)  counts[t] = 0;
    if (t < 256) colsum[t] = 0.f;
}

// copy X -> Xv (bf16) rows [0,NN), accumulate column partial sums (fp32)
__global__ __launch_bounds__(256) void vnode_partial(const float* __restrict__ X,
                                                     ushort* __restrict__ Xv,
                                                     float* __restrict__ colsum) {
    int j  = threadIdx.x;
    int r0 = blockIdx.x * 64;
    int re = min(r0 + 64, NN);
    float s = 0.f;
    for (int r = r0; r < re; ++r) {
        float v = X[(size_t)r * IND + j];
        Xv[(size_t)r * IND + j] = f2bf(v);
        s += v;
    }
    atomicAdd(&colsum[j], s);
}

__global__ __launch_bounds__(256) void vnode_finalize(const float* __restrict__ colsum,
                                                      ushort* __restrict__ Xv) {
    int j = threadIdx.x;
    Xv[(size_t)NN * IND + j] = f2bf(colsum[j] * (1.0f / NN));
}

// W[K][256] fp32 -> Wt[256][K] bf16 (transposed for MFMA B-fragments)
__global__ __launch_bounds__(256) void conv_w(const float* __restrict__ W,
                                              ushort* __restrict__ Wt, int K) {
    int t = blockIdx.x * 256 + threadIdx.x;
    if (t < K * 256) {
        int k = t >> 8, n = t & 255;
        Wt[n * K + k] = f2bf(W[t]);
    }
}

// Wout[128][64] fp32 -> Wto[64][128] bf16
__global__ __launch_bounds__(256) void conv_wout(const float* __restrict__ W,
                                                 ushort* __restrict__ Wt) {
    int t = blockIdx.x * 256 + threadIdx.x;
    if (t < HD * 64) {
        int k = t >> 6, n = t & 63;
        Wt[n * HD + k] = f2bf(W[t]);
    }
}

__global__ __launch_bounds__(256) void count_kernel(const int* __restrict__ ei, int* __restrict__ counts) {
    int e = blockIdx.x * 256 + threadIdx.x;
    if (e < NE) atomicAdd(&counts[ei[NE + e]], 1);
}

// parallel scan, pass 1: per-block exclusive scan + block sums
__global__ __launch_bounds__(256) void scan1_kernel(const int* __restrict__ counts,
                                                    int* __restrict__ row_start,
                                                    int* __restrict__ blocksums) {
    __shared__ int s[256];
    int t = threadIdx.x, i = blockIdx.x * 256 + t;
    int v = (i < NN) ? counts[i] : 0;
    s[t] = v;
    __syncthreads();
    for (int off = 1; off < 256; off <<= 1) {
        int u = (t >= off) ? s[t - off] : 0;
        __syncthreads();
        s[t] += u;
        __syncthreads();
    }
    if (i < NN) row_start[i] = s[t] - v;      // local exclusive
    if (t == 255) blocksums[blockIdx.x] = s[255];
}

// pass 2: scan the 196 block sums (one block)
__global__ __launch_bounds__(256) void scan2_kernel(const int* __restrict__ blocksums,
                                                    int* __restrict__ blockoffs) {
    __shared__ int s[256];
    int t = threadIdx.x;
    int v = (t < NBLK) ? blocksums[t] : 0;
    s[t] = v;
    __syncthreads();
    for (int off = 1; off < 256; off <<= 1) {
        int u = (t >= off) ? s[t - off] : 0;
        __syncthreads();
        s[t] += u;
        __syncthreads();
    }
    if (t < NBLK) blockoffs[t] = s[t] - v;    // exclusive
}

// pass 3: add block offsets, init cursor, set row_start[NN]
__global__ __launch_bounds__(256) void scan3_kernel(int* __restrict__ row_start,
                                                    const int* __restrict__ blockoffs,
                                                    int* __restrict__ cursor) {
    int i = blockIdx.x * 256 + threadIdx.x;
    if (i < NN) {
        int r = row_start[i] + blockoffs[blockIdx.x];
        row_start[i] = r;
        cursor[i]    = r;
    }
    if (i == 0) row_start[NN] = NE;
}

__global__ __launch_bounds__(256) void fill_kernel(const int* __restrict__ ei,
                                                   int* __restrict__ cursor,
                                                   int* __restrict__ csr) {
    int e = blockIdx.x * 256 + threadIdx.x;
    if (e < NE) {
        int d   = ei[NE + e];
        int pos = atomicAdd(&cursor[d], 1);
        csr[pos] = ei[e];
    }
}

// ---------------- per-layer kernels ----------------

// H[NV][256](bf16) = A[NV][K](bf16) @ Wt[256][K]^T(bf16), fp32 acc via MFMA.
// Fused epilogue: as_[n][2], ad_[n][2] = sum_c H[n][c]*a_{s,d}[c].
// Block = 256 thr (4 waves); wave computes 16 rows x 256 cols; no LDS.
template <int K>
__global__ __launch_bounds__(256) void gemm_mfma(const ushort* __restrict__ A,
                                                 const ushort* __restrict__ Bt,
                                                 const float* __restrict__ a_s,
                                                 const float* __restrict__ a_d,
                                                 ushort* __restrict__ H,
                                                 float* __restrict__ as_,
                                                 float* __restrict__ ad_) {
    int wave = threadIdx.x >> 6, lane = threadIdx.x & 63;
    int r0   = blockIdx.x * 64 + wave * 16;
    int lrow = lane & 15, lk = lane >> 4;          // A: row=lrow, k-block=lk ; B: col=lrow
    int arow = min(r0 + lrow, NV - 1);
    const ushort* Ap = A  + (size_t)arow * K + lk * 8;
    const ushort* Bp = Bt + (size_t)lrow * K + lk * 8;

    f32x4 acc[16] = {};
    for (int k0 = 0; k0 < K; k0 += 32) {
        short8 af = *reinterpret_cast<const short8*>(Ap + k0);
#pragma unroll
        for (int f = 0; f < 16; ++f) {
            short8 bfr = *reinterpret_cast<const short8*>(Bp + k0 + (size_t)f * 16 * K);
            acc[f] = __builtin_amdgcn_mfma_f32_16x16x32_bf16(af, bfr, acc[f], 0, 0, 0);
        }
    }

    // C/D layout: col = 16f + lrow, row = r0 + lk*4 + r
#pragma unroll
    for (int f = 0; f < 16; ++f) {
        int c = 16 * f + lrow;
#pragma unroll
        for (int r = 0; r < 4; ++r) {
            int row = r0 + lk * 4 + r;
            if (row < NV) H[(size_t)row * NHC + c] = f2bf(acc[f][r]);
        }
    }

    // fused alpha: coefficient flat index == column index (a_src is [2][128] flat)
    float cs[16], cd[16];
#pragma unroll
    for (int f = 0; f < 16; ++f) {
        cs[f] = a_s[16 * f + lrow];
        cd[f] = a_d[16 * f + lrow];
    }
#pragma unroll
    for (int r = 0; r < 4; ++r) {
        float s0 = 0.f, s1 = 0.f, d0 = 0.f, d1 = 0.f;
#pragma unroll
        for (int f = 0; f < 8; ++f)  { s0 += acc[f][r] * cs[f]; d0 += acc[f][r] * cd[f]; }
#pragma unroll
        for (int f = 8; f < 16; ++f) { s1 += acc[f][r] * cs[f]; d1 += acc[f][r] * cd[f]; }
        // reduce across the 16 lrow lanes (lk bits untouched by xor<16)
        for (int off = 1; off < 16; off <<= 1) {
            s0 += __shfl_xor(s0, off); s1 += __shfl_xor(s1, off);
            d0 += __shfl_xor(d0, off); d1 += __shfl_xor(d1, off);
        }
        int row = r0 + lk * 4 + r;
        if (lrow == 0 && row < NV) {
            as_[row * 2] = s0; as_[row * 2 + 1] = s1;
            ad_[row * 2] = d0; ad_[row * 2 + 1] = d1;
        }
    }
}

__global__ __launch_bounds__(256) void init_virt(int* vm, float* vden, float* vacc) {
    int t = threadIdx.x;
    vacc[t] = 0.f;
    if (t < 2) { vm[t] = INT_MIN; vden[t] = 0.f; }
}

// max over all NV in-edges of the virtual node
__global__ __launch_bounds__(256) void vmax_kernel(const float* __restrict__ as_,
                                                   const float* __restrict__ ad_,
                                                   int* __restrict__ vm) {
    float ad0 = ad_[NN * 2], ad1 = ad_[NN * 2 + 1];
    float m0 = -INFINITY, m1 = -INFINITY;
    for (int r = blockIdx.x * 256 + threadIdx.x; r < NV; r += gridDim.x * 256) {
        m0 = fmaxf(m0, lrelu(as_[r * 2] + ad0));
        m1 = fmaxf(m1, lrelu(as_[r * 2 + 1] + ad1));
    }
    for (int off = 32; off; off >>= 1) {
        m0 = fmaxf(m0, __shfl_xor(m0, off));
        m1 = fmaxf(m1, __shfl_xor(m1, off));
    }
    __shared__ float lm0[4], lm1[4];
    int wave = threadIdx.x >> 6, lane = threadIdx.x & 63;
    if (lane == 0) { lm0[wave] = m0; lm1[wave] = m1; }
    __syncthreads();
    if (threadIdx.x == 0) {
        m0 = fmaxf(fmaxf(lm0[0], lm0[1]), fmaxf(lm0[2], lm0[3]));
        m1 = fmaxf(fmaxf(lm1[0], lm1[1]), fmaxf(lm1[2], lm1[3]));
        atomicMax(&vm[0], fkey(m0));
        atomicMax(&vm[1], fkey(m1));
    }
}

// weighted sum over all NV rows into vacc[256], denom into vden[2]
__global__ __launch_bounds__(256) void vsum_kernel(const float* __restrict__ as_,
                                                   const float* __restrict__ ad_,
                                                   const ushort* __restrict__ H,
                                                   const int* __restrict__ vm,
                                                   float* __restrict__ vden,
                                                   float* __restrict__ vacc) {
    int j = threadIdx.x;
    int h = j >> 7;
    float adh = ad_[NN * 2 + h];
    float mh  = funkey(vm[h]);
    int r0 = blockIdx.x * 64, re = min(r0 + 64, NV);
    float acc = 0.f, dsum = 0.f;
    for (int r = r0; r < re; ++r) {
        float e = lrelu(as_[r * 2 + h] + adh);
        float w = __expf(e - mh);
        acc += w * bf2f(H[(size_t)r * NHC + j]);
        dsum += w;
    }
    atomicAdd(&vacc[j], acc);
    if ((j & 127) == 0) atomicAdd(&vden[h], dsum);
}

// virtual-node epilogue: normalize, mean heads, bias, LN, gelu
__global__ __launch_bounds__(256) void vpost_kernel(const float* __restrict__ vacc,
                                                    const float* __restrict__ vden,
                                                    const float* __restrict__ b,
                                                    const float* __restrict__ g,
                                                    const float* __restrict__ be,
                                                    ushort* __restrict__ hn) {
    __shared__ float o[256];
    __shared__ float red[256];
    int j = threadIdx.x, h = j >> 7;
    o[j] = vacc[j] / (vden[h] + 1e-16f);
    __syncthreads();
    float y = 0.f;
    if (j < HD) y = 0.5f * (o[j] + o[j + HD]) + b[j];
    red[j] = (j < HD) ? y : 0.f;
    __syncthreads();
    for (int s = 64; s; s >>= 1) { if (j < s) red[j] += red[j + s]; __syncthreads(); }
    float mu = red[0] * (1.f / HD);
    __syncthreads();
    float c = (j < HD) ? (y - mu) : 0.f;
    red[j] = c * c;
    __syncthreads();
    for (int s = 64; s; s >>= 1) { if (j < s) red[j] += red[j + s]; __syncthreads(); }
    float var = red[0] * (1.f / HD);
    if (j < HD) {
        float xn = (y - mu) * rsqrtf(var + 1e-5f) * g[j] + be[j];
        hn[(size_t)NN * HD + j] = f2bf(gelu(xn));
    }
}

// regular nodes: one wave per dst node; softmax over {csr edges, virtual, self};
// aggregate + mean-heads + bias + LN + gelu fused.
// Lane l owns column pair (2l, 2l+1) of each head -> ushort2 gathers.
__global__ __launch_bounds__(256) void node_kernel(const int* __restrict__ row_start,
                                                   const int* __restrict__ csr,
                                                   const float* __restrict__ as_,
                                                   const float* __restrict__ ad_,
                                                   const ushort* __restrict__ H,
                                                   const float* __restrict__ b,
                                                   const float* __restrict__ g,
                                                   const float* __restrict__ be,
                                                   ushort* __restrict__ hn) {
    int wave = threadIdx.x >> 6, lane = threadIdx.x & 63;
    int i = blockIdx.x * 4 + wave;
    if (i >= NN) return;
    int rs = row_start[i], cnt = row_start[i + 1] - rs;
    int tot = cnt + 2; // + virtual, + self
    float ad0 = ad_[i * 2], ad1 = ad_[i * 2 + 1];

    // phase A: online softmax stats per head
    float m0 = -INFINITY, d0 = 0.f, m1 = -INFINITY, d1 = 0.f;
    for (int idx = lane; idx < tot; idx += 64) {
        int src = idx < cnt ? csr[rs + idx] : (idx == cnt ? NN : i);
        float e0 = lrelu(as_[src * 2] + ad0);
        float e1 = lrelu(as_[src * 2 + 1] + ad1);
        md_merge(m0, d0, e0, 1.f);
        md_merge(m1, d1, e1, 1.f);
    }
    for (int off = 32; off; off >>= 1) {
        float mm0 = __shfl_xor(m0, off), dd0 = __shfl_xor(d0, off);
        float mm1 = __shfl_xor(m1, off), dd1 = __shfl_xor(d1, off);
        md_merge(m0, d0, mm0, dd0);
        md_merge(m1, d1, mm1, dd1);
    }
    float r0 = 1.f / (d0 + 1e-16f), r1 = 1.f / (d1 + 1e-16f);

    // phase B: weighted aggregation; lane owns cols (2l,2l+1) and (128+2l,128+2l+1)
    float a0 = 0.f, a1 = 0.f, a2 = 0.f, a3 = 0.f;
    for (int jj = 0; jj < tot; ++jj) {
        int src = jj < cnt ? csr[rs + jj] : (jj == cnt ? NN : i);
        float e0 = lrelu(as_[src * 2] + ad0);
        float e1 = lrelu(as_[src * 2 + 1] + ad1);
        float w0 = __expf(e0 - m0) * r0;
        float w1 = __expf(e1 - m1) * r1;
        const ushort2* hr2 = reinterpret_cast<const ushort2*>(H + (size_t)src * NHC);
        ushort2 p0 = hr2[lane];
        ushort2 p1 = hr2[64 + lane];
        a0 += w0 * bf2f(p0.x);
        a1 += w0 * bf2f(p0.y);
        a2 += w1 * bf2f(p1.x);
        a3 += w1 * bf2f(p1.y);
    }

    // epilogue: mean over heads + bias (cols 2l, 2l+1 of the 128-dim vector)
    int c0 = 2 * lane, c1 = 2 * lane + 1;
    float ya = 0.5f * (a0 + a2) + b[c0];
    float yb = 0.5f * (a1 + a3) + b[c1];
    // LN over 128 (2 values per lane)
    float s = ya + yb;
    for (int off = 32; off; off >>= 1) s += __shfl_xor(s, off);
    float mu = s * (1.f / HD);
    float ca = ya - mu, cb = yb - mu;
    float v = ca * ca + cb * cb;
    for (int off = 32; off; off >>= 1) v += __shfl_xor(v, off);
    float rstd = rsqrtf(v * (1.f / HD) + 1e-5f);
    float xa = ca * rstd * g[c0] + be[c0];
    float xb = cb * rstd * g[c1] + be[c1];
    ushort2 o2 = {f2bf(gelu(xa)), f2bf(gelu(xb))};
    *reinterpret_cast<ushort2*>(&hn[(size_t)i * HD + c0]) = o2;
}

// out[NN][64] = h[NN][128](bf16) @ Wto[64][128]^T(bf16) + bout, via MFMA
__global__ __launch_bounds__(256) void out_mfma(const ushort* __restrict__ A,
                                                const ushort* __restrict__ Bt,
                                                const float* __restrict__ bout,
                                                float* __restrict__ out) {
    int wave = threadIdx.x >> 6, lane = threadIdx.x & 63;
    int r0   = blockIdx.x * 64 + wave * 16;
    int lrow = lane & 15, lk = lane >> 4;
    int arow = min(r0 + lrow, NN - 1);
    const ushort* Ap = A  + (size_t)arow * HD + lk * 8;
    const ushort* Bp = Bt + (size_t)lrow * HD + lk * 8;

    f32x4 acc[4] = {};
#pragma unroll
    for (int k0 = 0; k0 < HD; k0 += 32) {
        short8 af = *reinterpret_cast<const short8*>(Ap + k0);
#pragma unroll
        for (int f = 0; f < 4; ++f) {
            short8 bfr = *reinterpret_cast<const short8*>(Bp + k0 + (size_t)f * 16 * HD);
            acc[f] = __builtin_amdgcn_mfma_f32_16x16x32_bf16(af, bfr, acc[f], 0, 0, 0);
        }
    }
#pragma unroll
    for (int f = 0; f < 4; ++f) {
        int c = 16 * f + lrow;
        float bc = bout[c];
#pragma unroll
        for (int r = 0; r < 4; ++r) {
            int row = r0 + lk * 4 + r;
            if (row < NN) out[(size_t)row * 64 + c] = acc[f][r] + bc;
        }
    }
}

// ---------------- launcher ----------------

extern "C" void kernel_launch(void* const* d_in, const int* in_sizes, int n_in,
                              void* d_out, int out_size, void* d_ws, size_t ws_size,
                              hipStream_t stream) {
    (void)in_sizes; (void)n_in; (void)out_size; (void)ws_size;

    const float* X  = (const float*)d_in[0];
    const int*   ei = (const int*)d_in[1];
    const float* W[3]   = {(const float*)d_in[3],  (const float*)d_in[9],  (const float*)d_in[15]};
    const float* Asp[3] = {(const float*)d_in[4],  (const float*)d_in[10], (const float*)d_in[16]};
    const float* Adp[3] = {(const float*)d_in[5],  (const float*)d_in[11], (const float*)d_in[17]};
    const float* Bb[3]  = {(const float*)d_in[6],  (const float*)d_in[12], (const float*)d_in[18]};
    const float* Gg[3]  = {(const float*)d_in[7],  (const float*)d_in[13], (const float*)d_in[19]};
    const float* Be[3]  = {(const float*)d_in[8],  (const float*)d_in[14], (const float*)d_in[20]};
    const float* Wout = (const float*)d_in[21];
    const float* bout = (const float*)d_in[22];
    float* out = (float*)d_out;

    uintptr_t base = (uintptr_t)d_ws;
    auto take = [&](size_t bytes) {
        uintptr_t p = base;
        base += (bytes + 255) & ~(size_t)255;
        return p;
    };
    ushort* Xv    = (ushort*)take((size_t)NV * IND * 2);
    ushort* Hbuf  = (ushort*)take((size_t)NV * NHC * 2);
    ushort* hA    = (ushort*)take((size_t)NV * HD * 2);
    ushort* hB    = (ushort*)take((size_t)NV * HD * 2);
    ushort* Wt0   = (ushort*)take((size_t)256 * IND * 2);
    ushort* Wt1   = (ushort*)take((size_t)256 * HD * 2);
    ushort* Wt2   = (ushort*)take((size_t)256 * HD * 2);
    ushort* Wto   = (ushort*)take((size_t)64 * HD * 2);
    float* as_    = (float*)take((size_t)NV * 2 * 4);
    float* ad_    = (float*)take((size_t)NV * 2 * 4);
    float* colsum = (float*)take(256 * 4);
    int*   counts = (int*)take((size_t)NN * 4);
    int*   rowst  = (int*)take((size_t)(NN + 1) * 4);
    int*   cursor = (int*)take((size_t)NN * 4);
    int*   csr    = (int*)take((size_t)NE * 4);
    int*   bsums  = (int*)take((size_t)NBLK * 4);
    int*   boffs  = (int*)take((size_t)NBLK * 4);
    int*   vm     = (int*)take(2 * 4);
    float* vden   = (float*)take(2 * 4);
    float* vacc   = (float*)take(256 * 4);
    ushort* Wt[3] = {Wt0, Wt1, Wt2};

    // setup
    zero_init<<<196, 256, 0, stream>>>(counts, colsum);
    vnode_partial<<<(NN + 63) / 64, 256, 0, stream>>>(X, Xv, colsum);
    vnode_finalize<<<1, 256, 0, stream>>>(colsum, Xv);
    conv_w<<<(IND * 256 + 255) / 256, 256, 0, stream>>>(W[0], Wt0, IND);
    conv_w<<<(HD  * 256 + 255) / 256, 256, 0, stream>>>(W[1], Wt1, HD);
    conv_w<<<(HD  * 256 + 255) / 256, 256, 0, stream>>>(W[2], Wt2, HD);
    conv_wout<<<(HD * 64 + 255) / 256, 256, 0, stream>>>(Wout, Wto);
    count_kernel<<<(NE + 255) / 256, 256, 0, stream>>>(ei, counts);
    scan1_kernel<<<NBLK, 256, 0, stream>>>(counts, rowst, bsums);
    scan2_kernel<<<1, 256, 0, stream>>>(bsums, boffs);
    scan3_kernel<<<NBLK, 256, 0, stream>>>(rowst, boffs, cursor);
    fill_kernel<<<(NE + 255) / 256, 256, 0, stream>>>(ei, cursor, csr);

    const ushort* hin = Xv;
    ushort* houts[3] = {hA, hB, hA};
    for (int li = 0; li < 3; ++li) {
        if (li == 0)
            gemm_mfma<IND><<<(NV + 63) / 64, 256, 0, stream>>>(hin, Wt[li], Asp[li], Adp[li], Hbuf, as_, ad_);
        else
            gemm_mfma<HD><<<(NV + 63) / 64, 256, 0, stream>>>(hin, Wt[li], Asp[li], Adp[li], Hbuf, as_, ad_);
        init_virt<<<1, 256, 0, stream>>>(vm, vden, vacc);
        vmax_kernel<<<128, 256, 0, stream>>>(as_, ad_, vm);
        vsum_kernel<<<(NV + 63) / 64, 256, 0, stream>>>(as_, ad_, Hbuf, vm, vden, vacc);
        vpost_kernel<<<1, 256, 0, stream>>>(vacc, vden, Bb[li], Gg[li], Be[li], houts[li]);
        node_kernel<<<(NN + 3) / 4, 256, 0, stream>>>(rowst, csr, as_, ad_, Hbuf,
                                                      Bb[li], Gg[li], Be[li], houts[li]);
        hin = houts[li];
    }
    out_mfma<<<(NN + 63) / 64, 256, 0, stream>>>(hin, Wto, bout, out);
}

// Round 4
// 654.776 us; speedup vs baseline: 1.7238x; 1.1672x over previous
//
#include <hip/hip_runtime.h>
#include <cmath>
#include <climits>

#define DEV __device__ __forceinline__

constexpr int NN  = 50000;    // real nodes
constexpr int NE  = 400000;   // regular edges
constexpr int NV  = NN + 1;   // + virtual node
constexpr int IND = 256;      // input dim
constexpr int HD  = 128;      // hidden dim
constexpr int NHC = 256;      // heads * hidden = GEMM N
constexpr int NBLK = (NN + 255) / 256;  // 196 scan blocks

typedef short short8 __attribute__((ext_vector_type(8)));
typedef float f32x4  __attribute__((ext_vector_type(4)));

DEV float lrelu(float x) { return x > 0.f ? x : 0.2f * x; }
DEV float gelu(float x)  { return x * 0.5f * (1.f + erff(x * 0.70710678118654752f)); }
// bf16 storage as ushort; RNE convert
DEV ushort f2bf(float f) { uint u = __float_as_uint(f); return (ushort)((u + 0x7FFFu + ((u >> 16) & 1u)) >> 16); }
DEV float  bf2f(ushort h) { return __uint_as_float((uint)h << 16); }

// ---------------- setup kernels ----------------

__global__ __launch_bounds__(256) void zero_init(int* counts, float* colsum) {
    int t = blockIdx.x * 256 + threadIdx.x;
    if (t < NN)  counts[t] = 0;
    if (t < 256) colsum[t] = 0.f;
}

// copy X -> Xv (bf16) rows [0,NN), accumulate column partial sums (fp32)
__global__ __launch_bounds__(256) void vnode_partial(const float* __restrict__ X,
                                                     ushort* __restrict__ Xv,
                                                     float* __restrict__ colsum) {
    int j  = threadIdx.x;
    int r0 = blockIdx.x * 64;
    int re = min(r0 + 64, NN);
    float s = 0.f;
    for (int r = r0; r < re; ++r) {
        float v = X[(size_t)r * IND + j];
        Xv[(size_t)r * IND + j] = f2bf(v);
        s += v;
    }
    atomicAdd(&colsum[j], s);
}

// fused: W0/W1/W2 -> Wt (transposed bf16), Wout -> Wto, colsum -> Xv virtual row
__global__ __launch_bounds__(256) void conv_all(const float* __restrict__ W0,
                                                const float* __restrict__ W1,
                                                const float* __restrict__ W2,
                                                const float* __restrict__ Wout,
                                                ushort* __restrict__ Wt0,
                                                ushort* __restrict__ Wt1,
                                                ushort* __restrict__ Wt2,
                                                ushort* __restrict__ Wto,
                                                const float* __restrict__ colsum,
                                                ushort* __restrict__ Xv) {
    int bid = blockIdx.x, t = threadIdx.x;
    if (bid < 256) {               // W0: [256][256] -> Wt0 [256][256]
        int idx = bid * 256 + t;
        int k = idx >> 8, n = idx & 255;
        Wt0[n * IND + k] = f2bf(W0[idx]);
    } else if (bid < 384) {        // W1: [128][256] -> Wt1 [256][128]
        int idx = (bid - 256) * 256 + t;
        int k = idx >> 8, n = idx & 255;
        Wt1[n * HD + k] = f2bf(W1[idx]);
    } else if (bid < 512) {        // W2
        int idx = (bid - 384) * 256 + t;
        int k = idx >> 8, n = idx & 255;
        Wt2[n * HD + k] = f2bf(W2[idx]);
    } else if (bid < 544) {        // Wout: [128][64] -> Wto [64][128]
        int idx = (bid - 512) * 256 + t;
        int k = idx >> 6, n = idx & 63;
        Wto[n * HD + k] = f2bf(Wout[idx]);
    } else {                       // virtual node row
        Xv[(size_t)NN * IND + t] = f2bf(colsum[t] * (1.0f / NN));
    }
}

__global__ __launch_bounds__(256) void count_kernel(const int* __restrict__ ei, int* __restrict__ counts) {
    int e = blockIdx.x * 256 + threadIdx.x;
    if (e < NE) atomicAdd(&counts[ei[NE + e]], 1);
}

// parallel scan, pass 1: per-block exclusive scan + block sums
__global__ __launch_bounds__(256) void scan1_kernel(const int* __restrict__ counts,
                                                    int* __restrict__ row_start,
                                                    int* __restrict__ blocksums) {
    __shared__ int s[256];
    int t = threadIdx.x, i = blockIdx.x * 256 + t;
    int v = (i < NN) ? counts[i] : 0;
    s[t] = v;
    __syncthreads();
    for (int off = 1; off < 256; off <<= 1) {
        int u = (t >= off) ? s[t - off] : 0;
        __syncthreads();
        s[t] += u;
        __syncthreads();
    }
    if (i < NN) row_start[i] = s[t] - v;      // local exclusive
    if (t == 255) blocksums[blockIdx.x] = s[255];
}

// pass 2: scan the 196 block sums (one block)
__global__ __launch_bounds__(256) void scan2_kernel(const int* __restrict__ blocksums,
                                                    int* __restrict__ blockoffs) {
    __shared__ int s[256];
    int t = threadIdx.x;
    int v = (t < NBLK) ? blocksums[t] : 0;
    s[t] = v;
    __syncthreads();
    for (int off = 1; off < 256; off <<= 1) {
        int u = (t >= off) ? s[t - off] : 0;
        __syncthreads();
        s[t] += u;
        __syncthreads();
    }
    if (t < NBLK) blockoffs[t] = s[t] - v;    // exclusive
}

// pass 3: add block offsets, init cursor, set row_start[NN]
__global__ __launch_bounds__(256) void scan3_kernel(int* __restrict__ row_start,
                                                    const int* __restrict__ blockoffs,
                                                    int* __restrict__ cursor) {
    int i = blockIdx.x * 256 + threadIdx.x;
    if (i < NN) {
        int r = row_start[i] + blockoffs[blockIdx.x];
        row_start[i] = r;
        cursor[i]    = r;
    }
    if (i == 0) row_start[NN] = NE;
}

__global__ __launch_bounds__(256) void fill_kernel(const int* __restrict__ ei,
                                                   int* __restrict__ cursor,
                                                   int* __restrict__ csr) {
    int e = blockIdx.x * 256 + threadIdx.x;
    if (e < NE) {
        int d   = ei[NE + e];
        int pos = atomicAdd(&cursor[d], 1);
        csr[pos] = ei[e];
    }
}

// ---------------- per-layer kernels ----------------

// H[NV][256](bf16) = A[NV][K](bf16) @ Wt[256][K]^T(bf16), fp32 acc via MFMA.
// Fused: alpha epilogue; block 0 zeroes vacc/vden for the following vsum.
template <int K>
__global__ __launch_bounds__(256) void gemm_mfma(const ushort* __restrict__ A,
                                                 const ushort* __restrict__ Bt,
                                                 const float* __restrict__ a_s,
                                                 const float* __restrict__ a_d,
                                                 ushort* __restrict__ H,
                                                 float* __restrict__ as_,
                                                 float* __restrict__ ad_,
                                                 float* __restrict__ vacc,
                                                 float* __restrict__ vden) {
    if (blockIdx.x == 0) {                 // zero virtual-node accumulators
        vacc[threadIdx.x] = 0.f;
        if (threadIdx.x < 2) vden[threadIdx.x] = 0.f;
    }
    int wave = threadIdx.x >> 6, lane = threadIdx.x & 63;
    int r0   = blockIdx.x * 64 + wave * 16;
    int lrow = lane & 15, lk = lane >> 4;          // A: row=lrow, k-block=lk ; B: col=lrow
    int arow = min(r0 + lrow, NV - 1);
    const ushort* Ap = A  + (size_t)arow * K + lk * 8;
    const ushort* Bp = Bt + (size_t)lrow * K + lk * 8;

    f32x4 acc[16] = {};
    for (int k0 = 0; k0 < K; k0 += 32) {
        short8 af = *reinterpret_cast<const short8*>(Ap + k0);
#pragma unroll
        for (int f = 0; f < 16; ++f) {
            short8 bfr = *reinterpret_cast<const short8*>(Bp + k0 + (size_t)f * 16 * K);
            acc[f] = __builtin_amdgcn_mfma_f32_16x16x32_bf16(af, bfr, acc[f], 0, 0, 0);
        }
    }

    // C/D layout: col = 16f + lrow, row = r0 + lk*4 + r
#pragma unroll
    for (int f = 0; f < 16; ++f) {
        int c = 16 * f + lrow;
#pragma unroll
        for (int r = 0; r < 4; ++r) {
            int row = r0 + lk * 4 + r;
            if (row < NV) H[(size_t)row * NHC + c] = f2bf(acc[f][r]);
        }
    }

    // fused alpha: coefficient flat index == column index (a_src is [2][128] flat)
    float cs[16], cd[16];
#pragma unroll
    for (int f = 0; f < 16; ++f) {
        cs[f] = a_s[16 * f + lrow];
        cd[f] = a_d[16 * f + lrow];
    }
#pragma unroll
    for (int r = 0; r < 4; ++r) {
        float s0 = 0.f, s1 = 0.f, d0 = 0.f, d1 = 0.f;
#pragma unroll
        for (int f = 0; f < 8; ++f)  { s0 += acc[f][r] * cs[f]; d0 += acc[f][r] * cd[f]; }
#pragma unroll
        for (int f = 8; f < 16; ++f) { s1 += acc[f][r] * cs[f]; d1 += acc[f][r] * cd[f]; }
        for (int off = 1; off < 16; off <<= 1) {
            s0 += __shfl_xor(s0, off); s1 += __shfl_xor(s1, off);
            d0 += __shfl_xor(d0, off); d1 += __shfl_xor(d1, off);
        }
        int row = r0 + lk * 4 + r;
        if (lrow == 0 && row < NV) {
            as_[row * 2] = s0; as_[row * 2 + 1] = s1;
            ad_[row * 2] = d0; ad_[row * 2 + 1] = d1;
        }
    }
}

// weighted sum over all NV rows into vacc[256], denom into vden[2].
// Per-row weights computed once into LDS (no max subtraction; e bounded).
__global__ __launch_bounds__(256) void vsum_kernel(const float* __restrict__ as_,
                                                   const float* __restrict__ ad_,
                                                   const ushort* __restrict__ H,
                                                   float* __restrict__ vden,
                                                   float* __restrict__ vacc) {
    __shared__ float w0s[64], w1s[64];
    int j = threadIdx.x, h = j >> 7;
    int r0 = blockIdx.x * 64;
    if (j < 64) {
        int r = r0 + j;
        float p0 = 0.f, p1 = 0.f;
        if (r < NV) {
            float2 adv = *reinterpret_cast<const float2*>(ad_ + 2 * NN);
            float2 asv = *reinterpret_cast<const float2*>(as_ + 2 * r);
            p0 = __expf(lrelu(asv.x + adv.x));
            p1 = __expf(lrelu(asv.y + adv.y));
        }
        w0s[j] = p0; w1s[j] = p1;
    }
    __syncthreads();
    int re = min(r0 + 64, NV) - r0;
    float acc = 0.f, dsum = 0.f;
    for (int rr = 0; rr < re; ++rr) {
        float w = h ? w1s[rr] : w0s[rr];
        acc += w * bf2f(H[(size_t)(r0 + rr) * NHC + j]);
        dsum += w;
    }
    atomicAdd(&vacc[j], acc);
    if ((j & 127) == 0) atomicAdd(&vden[h], dsum);
}

// regular nodes: one wave per dst node. Unnormalized Σ p·H[src] with per-lane
// weight precompute + shfl broadcast; normalize after. Lane covers 4 cols of
// one head (ushort4 gather); head-mean via shfl_xor(32). Virtual node (i==NN)
// epilogue folded in (reads vacc/vden). LN + gelu fused.
__global__ __launch_bounds__(256) void node_kernel(const int* __restrict__ row_start,
                                                   const int* __restrict__ csr,
                                                   const float* __restrict__ as_,
                                                   const float* __restrict__ ad_,
                                                   const ushort* __restrict__ H,
                                                   const float* __restrict__ vacc,
                                                   const float* __restrict__ vden,
                                                   const float* __restrict__ b,
                                                   const float* __restrict__ g,
                                                   const float* __restrict__ be,
                                                   ushort* __restrict__ hn) {
    int wave = threadIdx.x >> 6, lane = threadIdx.x & 63;
    int i = blockIdx.x * 4 + wave;
    if (i > NN) return;
    int  l5 = lane & 31;
    bool h0 = lane < 32;

    float acc0 = 0.f, acc1 = 0.f, acc2 = 0.f, acc3 = 0.f, dp;
    if (i == NN) {
        int base = (h0 ? 0 : 128) + 4 * l5;
        acc0 = vacc[base];     acc1 = vacc[base + 1];
        acc2 = vacc[base + 2]; acc3 = vacc[base + 3];
        dp = vden[h0 ? 0 : 1];
    } else {
        int rs = row_start[i], cnt = row_start[i + 1] - rs;
        int tot = cnt + 2; // + virtual, + self
        float2 adv = *reinterpret_cast<const float2*>(ad_ + 2 * i);
        float dp0 = 0.f, dp1 = 0.f;
        for (int bse = 0; bse < tot; bse += 64) {
            int idx = bse + lane;
            int src_l = i; float p0_l = 0.f, p1_l = 0.f;
            if (idx < tot) {
                src_l = idx < cnt ? csr[rs + idx] : (idx == cnt ? NN : i);
                float2 asv = *reinterpret_cast<const float2*>(as_ + 2 * src_l);
                p0_l = __expf(lrelu(asv.x + adv.x));
                p1_l = __expf(lrelu(asv.y + adv.y));
                dp0 += p0_l; dp1 += p1_l;
            }
            int chunk = min(64, tot - bse);
            for (int j = 0; j < chunk; ++j) {
                int   src = __shfl(src_l, j);
                float w0  = __shfl(p0_l, j);
                float w1  = __shfl(p1_l, j);
                float w   = h0 ? w0 : w1;
                ushort4 q = reinterpret_cast<const ushort4*>(H + (size_t)src * NHC)[lane];
                acc0 += w * bf2f(q.x); acc1 += w * bf2f(q.y);
                acc2 += w * bf2f(q.z); acc3 += w * bf2f(q.w);
            }
        }
        for (int off = 32; off; off >>= 1) {
            dp0 += __shfl_xor(dp0, off);
            dp1 += __shfl_xor(dp1, off);
        }
        dp = h0 ? dp0 : dp1;
    }

    float r = 1.f / (dp + 1e-16f);
    float4 bv = reinterpret_cast<const float4*>(b)[l5];
    float z0 = acc0 * r, z1 = acc1 * r, z2 = acc2 * r, z3 = acc3 * r;
    float y0 = 0.5f * (z0 + __shfl_xor(z0, 32)) + bv.x;
    float y1 = 0.5f * (z1 + __shfl_xor(z1, 32)) + bv.y;
    float y2 = 0.5f * (z2 + __shfl_xor(z2, 32)) + bv.z;
    float y3 = 0.5f * (z3 + __shfl_xor(z3, 32)) + bv.w;
    // LN over 128 dims; each dim appears twice across the wave -> /256
    float s = y0 + y1 + y2 + y3;
    for (int off = 32; off; off >>= 1) s += __shfl_xor(s, off);
    float mu = s * (1.f / 256.f);
    float c0 = y0 - mu, c1 = y1 - mu, c2 = y2 - mu, c3 = y3 - mu;
    float v = c0 * c0 + c1 * c1 + c2 * c2 + c3 * c3;
    for (int off = 32; off; off >>= 1) v += __shfl_xor(v, off);
    float rstd = rsqrtf(v * (1.f / 256.f) + 1e-5f);
    if (h0) {
        float4 gv  = reinterpret_cast<const float4*>(g)[l5];
        float4 bev = reinterpret_cast<const float4*>(be)[l5];
        ushort4 o;
        o.x = f2bf(gelu(c0 * rstd * gv.x + bev.x));
        o.y = f2bf(gelu(c1 * rstd * gv.y + bev.y));
        o.z = f2bf(gelu(c2 * rstd * gv.z + bev.z));
        o.w = f2bf(gelu(c3 * rstd * gv.w + bev.w));
        *reinterpret_cast<ushort4*>(&hn[(size_t)i * HD + 4 * l5]) = o;
    }
}

// out[NN][64] = h[NN][128](bf16) @ Wto[64][128]^T(bf16) + bout, via MFMA
__global__ __launch_bounds__(256) void out_mfma(const ushort* __restrict__ A,
                                                const ushort* __restrict__ Bt,
                                                const float* __restrict__ bout,
                                                float* __restrict__ out) {
    int wave = threadIdx.x >> 6, lane = threadIdx.x & 63;
    int r0   = blockIdx.x * 64 + wave * 16;
    int lrow = lane & 15, lk = lane >> 4;
    int arow = min(r0 + lrow, NN - 1);
    const ushort* Ap = A  + (size_t)arow * HD + lk * 8;
    const ushort* Bp = Bt + (size_t)lrow * HD + lk * 8;

    f32x4 acc[4] = {};
#pragma unroll
    for (int k0 = 0; k0 < HD; k0 += 32) {
        short8 af = *reinterpret_cast<const short8*>(Ap + k0);
#pragma unroll
        for (int f = 0; f < 4; ++f) {
            short8 bfr = *reinterpret_cast<const short8*>(Bp + k0 + (size_t)f * 16 * HD);
            acc[f] = __builtin_amdgcn_mfma_f32_16x16x32_bf16(af, bfr, acc[f], 0, 0, 0);
        }
    }
#pragma unroll
    for (int f = 0; f < 4; ++f) {
        int c = 16 * f + lrow;
        float bc = bout[c];
#pragma unroll
        for (int r = 0; r < 4; ++r) {
            int row = r0 + lk * 4 + r;
            if (row < NN) out[(size_t)row * 64 + c] = acc[f][r] + bc;
        }
    }
}

// ---------------- launcher ----------------

extern "C" void kernel_launch(void* const* d_in, const int* in_sizes, int n_in,
                              void* d_out, int out_size, void* d_ws, size_t ws_size,
                              hipStream_t stream) {
    (void)in_sizes; (void)n_in; (void)out_size; (void)ws_size;

    const float* X  = (const float*)d_in[0];
    const int*   ei = (const int*)d_in[1];
    const float* W[3]   = {(const float*)d_in[3],  (const float*)d_in[9],  (const float*)d_in[15]};
    const float* Asp[3] = {(const float*)d_in[4],  (const float*)d_in[10], (const float*)d_in[16]};
    const float* Adp[3] = {(const float*)d_in[5],  (const float*)d_in[11], (const float*)d_in[17]};
    const float* Bb[3]  = {(const float*)d_in[6],  (const float*)d_in[12], (const float*)d_in[18]};
    const float* Gg[3]  = {(const float*)d_in[7],  (const float*)d_in[13], (const float*)d_in[19]};
    const float* Be[3]  = {(const float*)d_in[8],  (const float*)d_in[14], (const float*)d_in[20]};
    const float* Wout = (const float*)d_in[21];
    const float* bout = (const float*)d_in[22];
    float* out = (float*)d_out;

    uintptr_t base = (uintptr_t)d_ws;
    auto take = [&](size_t bytes) {
        uintptr_t p = base;
        base += (bytes + 255) & ~(size_t)255;
        return p;
    };
    ushort* Xv    = (ushort*)take((size_t)NV * IND * 2);
    ushort* Hbuf  = (ushort*)take((size_t)NV * NHC * 2);
    ushort* hA    = (ushort*)take((size_t)NV * HD * 2);
    ushort* hB    = (ushort*)take((size_t)NV * HD * 2);
    ushort* Wt0   = (ushort*)take((size_t)256 * IND * 2);
    ushort* Wt1   = (ushort*)take((size_t)256 * HD * 2);
    ushort* Wt2   = (ushort*)take((size_t)256 * HD * 2);
    ushort* Wto   = (ushort*)take((size_t)64 * HD * 2);
    float* as_    = (float*)take((size_t)NV * 2 * 4);
    float* ad_    = (float*)take((size_t)NV * 2 * 4);
    float* colsum = (float*)take(256 * 4);
    int*   counts = (int*)take((size_t)NN * 4);
    int*   rowst  = (int*)take((size_t)(NN + 1) * 4);
    int*   cursor = (int*)take((size_t)NN * 4);
    int*   csr    = (int*)take((size_t)NE * 4);
    int*   bsums  = (int*)take((size_t)NBLK * 4);
    int*   boffs  = (int*)take((size_t)NBLK * 4);
    float* vden   = (float*)take(2 * 4);
    float* vacc   = (float*)take(256 * 4);
    ushort* Wt[3] = {Wt0, Wt1, Wt2};

    // setup
    zero_init<<<196, 256, 0, stream>>>(counts, colsum);
    vnode_partial<<<(NN + 63) / 64, 256, 0, stream>>>(X, Xv, colsum);
    count_kernel<<<(NE + 255) / 256, 256, 0, stream>>>(ei, counts);
    scan1_kernel<<<NBLK, 256, 0, stream>>>(counts, rowst, bsums);
    scan2_kernel<<<1, 256, 0, stream>>>(bsums, boffs);
    scan3_kernel<<<NBLK, 256, 0, stream>>>(rowst, boffs, cursor);
    fill_kernel<<<(NE + 255) / 256, 256, 0, stream>>>(ei, cursor, csr);
    conv_all<<<545, 256, 0, stream>>>(W[0], W[1], W[2], Wout, Wt0, Wt1, Wt2, Wto, colsum, Xv);

    const ushort* hin = Xv;
    ushort* houts[3] = {hA, hB, hA};
    for (int li = 0; li < 3; ++li) {
        if (li == 0)
            gemm_mfma<IND><<<(NV + 63) / 64, 256, 0, stream>>>(hin, Wt[li], Asp[li], Adp[li], Hbuf, as_, ad_, vacc, vden);
        else
            gemm_mfma<HD><<<(NV + 63) / 64, 256, 0, stream>>>(hin, Wt[li], Asp[li], Adp[li], Hbuf, as_, ad_, vacc, vden);
        vsum_kernel<<<(NV + 63) / 64, 256, 0, stream>>>(as_, ad_, Hbuf, vden, vacc);
        node_kernel<<<NN / 4 + 1, 256, 0, stream>>>(rowst, csr, as_, ad_, Hbuf, vacc, vden,
                                                    Bb[li], Gg[li], Be[li], houts[li]);
        hin = houts[li];
    }
    out_mfma<<<(NN + 63) / 64, 256, 0, stream>>>(hin, Wto, bout, out);
}

// Round 5
// 564.361 us; speedup vs baseline: 2.0000x; 1.1602x over previous
//
#include <hip/hip_runtime.h>
#include <cmath>
#include <climits>

#define DEV __device__ __forceinline__

constexpr int NN  = 50000;    // real nodes
constexpr int NE  = 400000;   // regular edges
constexpr int NV  = NN + 1;   // + virtual node
constexpr int IND = 256;      // input dim
constexpr int HD  = 128;      // hidden dim
constexpr int NHC = 256;      // heads * hidden = GEMM N
constexpr int NBLK = (NN + 255) / 256;  // 196 scan blocks

typedef short short8 __attribute__((ext_vector_type(8)));
typedef float f32x4  __attribute__((ext_vector_type(4)));

DEV float lrelu(float x) { return x > 0.f ? x : 0.2f * x; }
DEV float gelu(float x)  { return x * 0.5f * (1.f + erff(x * 0.70710678118654752f)); }
// bf16 storage as ushort; RNE convert
DEV ushort f2bf(float f) { uint u = __float_as_uint(f); return (ushort)((u + 0x7FFFu + ((u >> 16) & 1u)) >> 16); }
DEV float  bf2f(ushort h) { return __uint_as_float((uint)h << 16); }

// async global->LDS, 16B per lane; dest = lds + lane*16 (wave-uniform base)
DEV void gload_lds16(const ushort* g, ushort* l) {
    __builtin_amdgcn_global_load_lds(
        (const __attribute__((address_space(1))) void*)g,
        (__attribute__((address_space(3))) void*)l,
        16, 0, 0);
}

// ---------------- setup kernels ----------------

__global__ __launch_bounds__(256) void zero_init(int* counts, float* colsum) {
    int t = blockIdx.x * 256 + threadIdx.x;
    if (t < NN)  counts[t] = 0;
    if (t < 256) colsum[t] = 0.f;
}

// copy X -> Xv (bf16) rows [0,NN), accumulate column partial sums (fp32)
__global__ __launch_bounds__(256) void vnode_partial(const float* __restrict__ X,
                                                     ushort* __restrict__ Xv,
                                                     float* __restrict__ colsum) {
    int j  = threadIdx.x;
    int r0 = blockIdx.x * 64;
    int re = min(r0 + 64, NN);
    float s = 0.f;
    for (int r = r0; r < re; ++r) {
        float v = X[(size_t)r * IND + j];
        Xv[(size_t)r * IND + j] = f2bf(v);
        s += v;
    }
    atomicAdd(&colsum[j], s);
}

// fused: W0/W1/W2 -> Wt (transposed bf16), Wout -> Wto, colsum -> Xv virtual row
__global__ __launch_bounds__(256) void conv_all(const float* __restrict__ W0,
                                                const float* __restrict__ W1,
                                                const float* __restrict__ W2,
                                                const float* __restrict__ Wout,
                                                ushort* __restrict__ Wt0,
                                                ushort* __restrict__ Wt1,
                                                ushort* __restrict__ Wt2,
                                                ushort* __restrict__ Wto,
                                                const float* __restrict__ colsum,
                                                ushort* __restrict__ Xv) {
    int bid = blockIdx.x, t = threadIdx.x;
    if (bid < 256) {               // W0: [256][256] -> Wt0 [256][256]
        int idx = bid * 256 + t;
        int k = idx >> 8, n = idx & 255;
        Wt0[n * IND + k] = f2bf(W0[idx]);
    } else if (bid < 384) {        // W1: [128][256] -> Wt1 [256][128]
        int idx = (bid - 256) * 256 + t;
        int k = idx >> 8, n = idx & 255;
        Wt1[n * HD + k] = f2bf(W1[idx]);
    } else if (bid < 512) {        // W2
        int idx = (bid - 384) * 256 + t;
        int k = idx >> 8, n = idx & 255;
        Wt2[n * HD + k] = f2bf(W2[idx]);
    } else if (bid < 544) {        // Wout: [128][64] -> Wto [64][128]
        int idx = (bid - 512) * 256 + t;
        int k = idx >> 6, n = idx & 63;
        Wto[n * HD + k] = f2bf(Wout[idx]);
    } else {                       // virtual node row
        Xv[(size_t)NN * IND + t] = f2bf(colsum[t] * (1.0f / NN));
    }
}

__global__ __launch_bounds__(256) void count_kernel(const int* __restrict__ ei, int* __restrict__ counts) {
    int e = blockIdx.x * 256 + threadIdx.x;
    if (e < NE) atomicAdd(&counts[ei[NE + e]], 1);
}

// parallel scan, pass 1: per-block exclusive scan + block sums
__global__ __launch_bounds__(256) void scan1_kernel(const int* __restrict__ counts,
                                                    int* __restrict__ row_start,
                                                    int* __restrict__ blocksums) {
    __shared__ int s[256];
    int t = threadIdx.x, i = blockIdx.x * 256 + t;
    int v = (i < NN) ? counts[i] : 0;
    s[t] = v;
    __syncthreads();
    for (int off = 1; off < 256; off <<= 1) {
        int u = (t >= off) ? s[t - off] : 0;
        __syncthreads();
        s[t] += u;
        __syncthreads();
    }
    if (i < NN) row_start[i] = s[t] - v;      // local exclusive
    if (t == 255) blocksums[blockIdx.x] = s[255];
}

// pass 2: scan the 196 block sums (one block)
__global__ __launch_bounds__(256) void scan2_kernel(const int* __restrict__ blocksums,
                                                    int* __restrict__ blockoffs) {
    __shared__ int s[256];
    int t = threadIdx.x;
    int v = (t < NBLK) ? blocksums[t] : 0;
    s[t] = v;
    __syncthreads();
    for (int off = 1; off < 256; off <<= 1) {
        int u = (t >= off) ? s[t - off] : 0;
        __syncthreads();
        s[t] += u;
        __syncthreads();
    }
    if (t < NBLK) blockoffs[t] = s[t] - v;    // exclusive
}

// pass 3: add block offsets, init cursor, set row_start[NN]
__global__ __launch_bounds__(256) void scan3_kernel(int* __restrict__ row_start,
                                                    const int* __restrict__ blockoffs,
                                                    int* __restrict__ cursor) {
    int i = blockIdx.x * 256 + threadIdx.x;
    if (i < NN) {
        int r = row_start[i] + blockoffs[blockIdx.x];
        row_start[i] = r;
        cursor[i]    = r;
    }
    if (i == 0) row_start[NN] = NE;
}

__global__ __launch_bounds__(256) void fill_kernel(const int* __restrict__ ei,
                                                   int* __restrict__ cursor,
                                                   int* __restrict__ csr) {
    int e = blockIdx.x * 256 + threadIdx.x;
    if (e < NE) {
        int d   = ei[NE + e];
        int pos = atomicAdd(&cursor[d], 1);
        csr[pos] = ei[e];
    }
}

// ---------------- per-layer kernels ----------------

// H[NV][256](bf16) = A[NV][K](bf16) @ Wt[256][K]^T(bf16), fp32 acc via MFMA.
// B k-slice staged in LDS (16KB) via global_load_lds; A direct global->reg.
// Block = 4 waves (2x2): wave = 32 rows x 128 cols (2x8 16x16 frags).
// Fused: alpha epilogue (wave wc covers exactly head wc); block 0 zeroes vacc/vden.
template <int K>
__global__ __launch_bounds__(256) void gemm_mfma(const ushort* __restrict__ A,
                                                 const ushort* __restrict__ Bt,
                                                 const float* __restrict__ a_s,
                                                 const float* __restrict__ a_d,
                                                 ushort* __restrict__ H,
                                                 float* __restrict__ as_,
                                                 float* __restrict__ ad_,
                                                 float* __restrict__ vacc,
                                                 float* __restrict__ vden) {
    __shared__ ushort Bs[256 * 32];            // [col][32 k] = 16KB
    if (blockIdx.x == 0) {                     // zero virtual-node accumulators
        vacc[threadIdx.x] = 0.f;
        if (threadIdx.x < 2) vden[threadIdx.x] = 0.f;
    }
    const int tid  = threadIdx.x;
    const int wave = tid >> 6, lane = tid & 63;
    const int wr   = wave >> 1, wc = wave & 1;
    const int lrow = lane & 15, lk = lane >> 4;
    const int r0   = blockIdx.x * 64 + wr * 32;

    int ar0 = min(r0 + lrow,      NV - 1);
    int ar1 = min(r0 + 16 + lrow, NV - 1);
    const ushort* Ap0 = A + (size_t)ar0 * K + lk * 8;
    const ushort* Ap1 = A + (size_t)ar1 * K + lk * 8;
    // B staging source: lane l covers col cb + l/4, k-slot l%4
    const int scol  = lane >> 2;
    const int sslot = lane & 3;

    f32x4 acc[2][8] = {};
    for (int k0 = 0; k0 < K; k0 += 32) {
#pragma unroll
        for (int q = 0; q < 4; ++q) {
            int cb = wave * 64 + q * 16;
            gload_lds16(Bt + (size_t)(cb + scol) * K + k0 + sslot * 8, &Bs[cb * 32]);
        }
        short8 a0 = *reinterpret_cast<const short8*>(Ap0 + k0);
        short8 a1 = *reinterpret_cast<const short8*>(Ap1 + k0);
        __syncthreads();                       // drains global_load_lds (vmcnt 0)
#pragma unroll
        for (int n = 0; n < 8; ++n) {
            short8 bf = *reinterpret_cast<const short8*>(&Bs[(wc * 128 + n * 16 + lrow) * 32 + lk * 8]);
            acc[0][n] = __builtin_amdgcn_mfma_f32_16x16x32_bf16(a0, bf, acc[0][n], 0, 0, 0);
            acc[1][n] = __builtin_amdgcn_mfma_f32_16x16x32_bf16(a1, bf, acc[1][n], 0, 0, 0);
        }
        __syncthreads();
    }

    // C/D layout: col = wc*128 + n*16 + lrow, row = r0 + m*16 + lk*4 + r
#pragma unroll
    for (int m = 0; m < 2; ++m)
#pragma unroll
        for (int n = 0; n < 8; ++n) {
            int c = wc * 128 + n * 16 + lrow;
#pragma unroll
            for (int r = 0; r < 4; ++r) {
                int row = r0 + m * 16 + lk * 4 + r;
                if (row < NV) H[(size_t)row * NHC + c] = f2bf(acc[m][n][r]);
            }
        }

    // fused alpha for head wc: coef flat index = wc*128 + col_within_head
    float cs[8], cd[8];
#pragma unroll
    for (int n = 0; n < 8; ++n) {
        cs[n] = a_s[wc * 128 + n * 16 + lrow];
        cd[n] = a_d[wc * 128 + n * 16 + lrow];
    }
#pragma unroll
    for (int m = 0; m < 2; ++m)
#pragma unroll
        for (int r = 0; r < 4; ++r) {
            float s = 0.f, d = 0.f;
#pragma unroll
            for (int n = 0; n < 8; ++n) {
                s += acc[m][n][r] * cs[n];
                d += acc[m][n][r] * cd[n];
            }
            for (int off = 1; off < 16; off <<= 1) {
                s += __shfl_xor(s, off);
                d += __shfl_xor(d, off);
            }
            int row = r0 + m * 16 + lk * 4 + r;
            if (lrow == 0 && row < NV) {
                as_[row * 2 + wc] = s;
                ad_[row * 2 + wc] = d;
            }
        }
}

// weighted sum over all NV rows into vacc[256], denom into vden[2].
// Per-row weights computed once into LDS (no max subtraction; e bounded).
__global__ __launch_bounds__(256) void vsum_kernel(const float* __restrict__ as_,
                                                   const float* __restrict__ ad_,
                                                   const ushort* __restrict__ H,
                                                   float* __restrict__ vden,
                                                   float* __restrict__ vacc) {
    __shared__ float w0s[64], w1s[64];
    int j = threadIdx.x, h = j >> 7;
    int r0 = blockIdx.x * 64;
    if (j < 64) {
        int r = r0 + j;
        float p0 = 0.f, p1 = 0.f;
        if (r < NV) {
            float2 adv = *reinterpret_cast<const float2*>(ad_ + 2 * NN);
            float2 asv = *reinterpret_cast<const float2*>(as_ + 2 * r);
            p0 = __expf(lrelu(asv.x + adv.x));
            p1 = __expf(lrelu(asv.y + adv.y));
        }
        w0s[j] = p0; w1s[j] = p1;
    }
    __syncthreads();
    int re = min(r0 + 64, NV) - r0;
    float acc = 0.f, dsum = 0.f;
    for (int rr = 0; rr < re; ++rr) {
        float w = h ? w1s[rr] : w0s[rr];
        acc += w * bf2f(H[(size_t)(r0 + rr) * NHC + j]);
        dsum += w;
    }
    atomicAdd(&vacc[j], acc);
    if ((j & 127) == 0) atomicAdd(&vden[h], dsum);
}

// regular nodes: one wave per dst node. Unnormalized Σ p·H[src] with per-lane
// weight precompute + shfl broadcast; normalize after. Lane covers 4 cols of
// one head (ushort4 gather); head-mean via shfl_xor(32). Virtual node (i==NN)
// epilogue folded in (reads vacc/vden). LN + gelu fused.
__global__ __launch_bounds__(256) void node_kernel(const int* __restrict__ row_start,
                                                   const int* __restrict__ csr,
                                                   const float* __restrict__ as_,
                                                   const float* __restrict__ ad_,
                                                   const ushort* __restrict__ H,
                                                   const float* __restrict__ vacc,
                                                   const float* __restrict__ vden,
                                                   const float* __restrict__ b,
                                                   const float* __restrict__ g,
                                                   const float* __restrict__ be,
                                                   ushort* __restrict__ hn) {
    int wave = threadIdx.x >> 6, lane = threadIdx.x & 63;
    int i = blockIdx.x * 4 + wave;
    if (i > NN) return;
    int  l5 = lane & 31;
    bool h0 = lane < 32;

    float acc0 = 0.f, acc1 = 0.f, acc2 = 0.f, acc3 = 0.f, dp;
    if (i == NN) {
        int base = (h0 ? 0 : 128) + 4 * l5;
        acc0 = vacc[base];     acc1 = vacc[base + 1];
        acc2 = vacc[base + 2]; acc3 = vacc[base + 3];
        dp = vden[h0 ? 0 : 1];
    } else {
        int rs = row_start[i], cnt = row_start[i + 1] - rs;
        int tot = cnt + 2; // + virtual, + self
        float2 adv = *reinterpret_cast<const float2*>(ad_ + 2 * i);
        float dp0 = 0.f, dp1 = 0.f;
        for (int bse = 0; bse < tot; bse += 64) {
            int idx = bse + lane;
            int src_l = i; float p0_l = 0.f, p1_l = 0.f;
            if (idx < tot) {
                src_l = idx < cnt ? csr[rs + idx] : (idx == cnt ? NN : i);
                float2 asv = *reinterpret_cast<const float2*>(as_ + 2 * src_l);
                p0_l = __expf(lrelu(asv.x + adv.x));
                p1_l = __expf(lrelu(asv.y + adv.y));
                dp0 += p0_l; dp1 += p1_l;
            }
            int chunk = min(64, tot - bse);
            for (int j = 0; j < chunk; ++j) {
                int   src = __shfl(src_l, j);
                float w0  = __shfl(p0_l, j);
                float w1  = __shfl(p1_l, j);
                float w   = h0 ? w0 : w1;
                ushort4 q = reinterpret_cast<const ushort4*>(H + (size_t)src * NHC)[lane];
                acc0 += w * bf2f(q.x); acc1 += w * bf2f(q.y);
                acc2 += w * bf2f(q.z); acc3 += w * bf2f(q.w);
            }
        }
        for (int off = 32; off; off >>= 1) {
            dp0 += __shfl_xor(dp0, off);
            dp1 += __shfl_xor(dp1, off);
        }
        dp = h0 ? dp0 : dp1;
    }

    float r = 1.f / (dp + 1e-16f);
    float4 bv = reinterpret_cast<const float4*>(b)[l5];
    float z0 = acc0 * r, z1 = acc1 * r, z2 = acc2 * r, z3 = acc3 * r;
    float y0 = 0.5f * (z0 + __shfl_xor(z0, 32)) + bv.x;
    float y1 = 0.5f * (z1 + __shfl_xor(z1, 32)) + bv.y;
    float y2 = 0.5f * (z2 + __shfl_xor(z2, 32)) + bv.z;
    float y3 = 0.5f * (z3 + __shfl_xor(z3, 32)) + bv.w;
    // LN over 128 dims; each dim appears twice across the wave -> /256
    float s = y0 + y1 + y2 + y3;
    for (int off = 32; off; off >>= 1) s += __shfl_xor(s, off);
    float mu = s * (1.f / 256.f);
    float c0 = y0 - mu, c1 = y1 - mu, c2 = y2 - mu, c3 = y3 - mu;
    float v = c0 * c0 + c1 * c1 + c2 * c2 + c3 * c3;
    for (int off = 32; off; off >>= 1) v += __shfl_xor(v, off);
    float rstd = rsqrtf(v * (1.f / 256.f) + 1e-5f);
    if (h0) {
        float4 gv  = reinterpret_cast<const float4*>(g)[l5];
        float4 bev = reinterpret_cast<const float4*>(be)[l5];
        ushort4 o;
        o.x = f2bf(gelu(c0 * rstd * gv.x + bev.x));
        o.y = f2bf(gelu(c1 * rstd * gv.y + bev.y));
        o.z = f2bf(gelu(c2 * rstd * gv.z + bev.z));
        o.w = f2bf(gelu(c3 * rstd * gv.w + bev.w));
        *reinterpret_cast<ushort4*>(&hn[(size_t)i * HD + 4 * l5]) = o;
    }
}

// out[NN][64] = h[NN][128](bf16) @ Wto[64][128]^T(bf16) + bout, via MFMA.
// B k-slice (64x32 = 4KB) staged in LDS; block = 4 waves x 32 rows = 128 rows.
__global__ __launch_bounds__(256) void out_mfma(const ushort* __restrict__ A,
                                                const ushort* __restrict__ Bt,
                                                const float* __restrict__ bout,
                                                float* __restrict__ out) {
    __shared__ ushort Bs[64 * 32];             // 4KB
    const int tid  = threadIdx.x;
    const int wave = tid >> 6, lane = tid & 63;
    const int lrow = lane & 15, lk = lane >> 4;
    const int r0   = blockIdx.x * 128 + wave * 32;

    int ar0 = min(r0 + lrow,      NN - 1);
    int ar1 = min(r0 + 16 + lrow, NN - 1);
    const ushort* Ap0 = A + (size_t)ar0 * HD + lk * 8;
    const ushort* Ap1 = A + (size_t)ar1 * HD + lk * 8;
    const int scol  = lane >> 2;
    const int sslot = lane & 3;

    f32x4 acc[2][4] = {};
#pragma unroll
    for (int k0 = 0; k0 < HD; k0 += 32) {
        int cb = wave * 16;                    // each wave stages 16 cols
        gload_lds16(Bt + (size_t)(cb + scol) * HD + k0 + sslot * 8, &Bs[cb * 32]);
        short8 a0 = *reinterpret_cast<const short8*>(Ap0 + k0);
        short8 a1 = *reinterpret_cast<const short8*>(Ap1 + k0);
        __syncthreads();
#pragma unroll
        for (int n = 0; n < 4; ++n) {
            short8 bf = *reinterpret_cast<const short8*>(&Bs[(n * 16 + lrow) * 32 + lk * 8]);
            acc[0][n] = __builtin_amdgcn_mfma_f32_16x16x32_bf16(a0, bf, acc[0][n], 0, 0, 0);
            acc[1][n] = __builtin_amdgcn_mfma_f32_16x16x32_bf16(a1, bf, acc[1][n], 0, 0, 0);
        }
        __syncthreads();
    }
#pragma unroll
    for (int m = 0; m < 2; ++m)
#pragma unroll
        for (int n = 0; n < 4; ++n) {
            int c = n * 16 + lrow;
            float bc = bout[c];
#pragma unroll
            for (int r = 0; r < 4; ++r) {
                int row = r0 + m * 16 + lk * 4 + r;
                if (row < NN) out[(size_t)row * 64 + c] = acc[m][n][r] + bc;
            }
        }
}

// ---------------- launcher ----------------

extern "C" void kernel_launch(void* const* d_in, const int* in_sizes, int n_in,
                              void* d_out, int out_size, void* d_ws, size_t ws_size,
                              hipStream_t stream) {
    (void)in_sizes; (void)n_in; (void)out_size; (void)ws_size;

    const float* X  = (const float*)d_in[0];
    const int*   ei = (const int*)d_in[1];
    const float* W[3]   = {(const float*)d_in[3],  (const float*)d_in[9],  (const float*)d_in[15]};
    const float* Asp[3] = {(const float*)d_in[4],  (const float*)d_in[10], (const float*)d_in[16]};
    const float* Adp[3] = {(const float*)d_in[5],  (const float*)d_in[11], (const float*)d_in[17]};
    const float* Bb[3]  = {(const float*)d_in[6],  (const float*)d_in[12], (const float*)d_in[18]};
    const float* Gg[3]  = {(const float*)d_in[7],  (const float*)d_in[13], (const float*)d_in[19]};
    const float* Be[3]  = {(const float*)d_in[8],  (const float*)d_in[14], (const float*)d_in[20]};
    const float* Wout = (const float*)d_in[21];
    const float* bout = (const float*)d_in[22];
    float* out = (float*)d_out;

    uintptr_t base = (uintptr_t)d_ws;
    auto take = [&](size_t bytes) {
        uintptr_t p = base;
        base += (bytes + 255) & ~(size_t)255;
        return p;
    };
    ushort* Xv    = (ushort*)take((size_t)NV * IND * 2);
    ushort* Hbuf  = (ushort*)take((size_t)NV * NHC * 2);
    ushort* hA    = (ushort*)take((size_t)NV * HD * 2);
    ushort* hB    = (ushort*)take((size_t)NV * HD * 2);
    ushort* Wt0   = (ushort*)take((size_t)256 * IND * 2);
    ushort* Wt1   = (ushort*)take((size_t)256 * HD * 2);
    ushort* Wt2   = (ushort*)take((size_t)256 * HD * 2);
    ushort* Wto   = (ushort*)take((size_t)64 * HD * 2);
    float* as_    = (float*)take((size_t)NV * 2 * 4);
    float* ad_    = (float*)take((size_t)NV * 2 * 4);
    float* colsum = (float*)take(256 * 4);
    int*   counts = (int*)take((size_t)NN * 4);
    int*   rowst  = (int*)take((size_t)(NN + 1) * 4);
    int*   cursor = (int*)take((size_t)NN * 4);
    int*   csr    = (int*)take((size_t)NE * 4);
    int*   bsums  = (int*)take((size_t)NBLK * 4);
    int*   boffs  = (int*)take((size_t)NBLK * 4);
    float* vden   = (float*)take(2 * 4);
    float* vacc   = (float*)take(256 * 4);
    ushort* Wt[3] = {Wt0, Wt1, Wt2};

    // setup
    zero_init<<<196, 256, 0, stream>>>(counts, colsum);
    vnode_partial<<<(NN + 63) / 64, 256, 0, stream>>>(X, Xv, colsum);
    count_kernel<<<(NE + 255) / 256, 256, 0, stream>>>(ei, counts);
    scan1_kernel<<<NBLK, 256, 0, stream>>>(counts, rowst, bsums);
    scan2_kernel<<<1, 256, 0, stream>>>(bsums, boffs);
    scan3_kernel<<<NBLK, 256, 0, stream>>>(rowst, boffs, cursor);
    fill_kernel<<<(NE + 255) / 256, 256, 0, stream>>>(ei, cursor, csr);
    conv_all<<<545, 256, 0, stream>>>(W[0], W[1], W[2], Wout, Wt0, Wt1, Wt2, Wto, colsum, Xv);

    const ushort* hin = Xv;
    ushort* houts[3] = {hA, hB, hA};
    for (int li = 0; li < 3; ++li) {
        if (li == 0)
            gemm_mfma<IND><<<(NV + 63) / 64, 256, 0, stream>>>(hin, Wt[li], Asp[li], Adp[li], Hbuf, as_, ad_, vacc, vden);
        else
            gemm_mfma<HD><<<(NV + 63) / 64, 256, 0, stream>>>(hin, Wt[li], Asp[li], Adp[li], Hbuf, as_, ad_, vacc, vden);
        vsum_kernel<<<(NV + 63) / 64, 256, 0, stream>>>(as_, ad_, Hbuf, vden, vacc);
        node_kernel<<<NN / 4 + 1, 256, 0, stream>>>(rowst, csr, as_, ad_, Hbuf, vacc, vden,
                                                    Bb[li], Gg[li], Be[li], houts[li]);
        hin = houts[li];
    }
    out_mfma<<<(NN + 127) / 128, 256, 0, stream>>>(hin, Wto, bout, out);
}

// Round 7
// 523.617 us; speedup vs baseline: 2.1556x; 1.0778x over previous
//
#include <hip/hip_runtime.h>
#include <cmath>
#include <climits>

#define DEV __device__ __forceinline__

constexpr int NN  = 50000;    // real nodes
constexpr int NE  = 400000;   // regular edges
constexpr int NV  = NN + 1;   // + virtual node
constexpr int IND = 256;      // input dim
constexpr int HD  = 128;      // hidden dim
constexpr int NHC = 256;      // heads * hidden = GEMM N
constexpr int NBLK = (NN + 255) / 256;  // 196 scan blocks
constexpr int VB   = (NN + 63) / 64;    // 782 vnode blocks
constexpr int CB   = (NE + 255) / 256;  // 1563 count blocks

typedef short short8 __attribute__((ext_vector_type(8)));
typedef float f32x4  __attribute__((ext_vector_type(4)));

DEV float lrelu(float x) { return x > 0.f ? x : 0.2f * x; }
DEV float gelu(float x)  { return x * 0.5f * (1.f + erff(x * 0.70710678118654752f)); }
// bf16 storage as ushort; RNE convert
DEV ushort f2bf(float f) { uint u = __float_as_uint(f); return (ushort)((u + 0x7FFFu + ((u >> 16) & 1u)) >> 16); }
DEV float  bf2f(ushort h) { return __uint_as_float((uint)h << 16); }
// wave-uniform lane broadcast via v_readlane (no LDS pipe)
DEV float rlane_f(float v, int j) { return __uint_as_float(__builtin_amdgcn_readlane(__float_as_uint(v), j)); }

// async global->LDS, 16B per lane; dest = lds + lane*16 (wave-uniform base)
DEV void gload_lds16(const ushort* g, ushort* l) {
    __builtin_amdgcn_global_load_lds(
        (const __attribute__((address_space(1))) void*)g,
        (__attribute__((address_space(3))) void*)l,
        16, 0, 0);
}

// ---------------- setup kernels ----------------

__global__ __launch_bounds__(256) void zero_init(int* counts, float* colsum) {
    int t = blockIdx.x * 256 + threadIdx.x;
    if (t < NN)  counts[t] = 0;
    if (t < 256) colsum[t] = 0.f;
}

// fused: blocks [0,VB): copy X -> Xv (bf16) + column partial sums;
//        blocks [VB, VB+CB): edge dst histogram
__global__ __launch_bounds__(256) void vnode_count(const float* __restrict__ X,
                                                   ushort* __restrict__ Xv,
                                                   float* __restrict__ colsum,
                                                   const int* __restrict__ ei,
                                                   int* __restrict__ counts) {
    if (blockIdx.x < VB) {
        int j  = threadIdx.x;
        int r0 = blockIdx.x * 64;
        int re = min(r0 + 64, NN);
        float s = 0.f;
        for (int r = r0; r < re; ++r) {
            float v = X[(size_t)r * IND + j];
            Xv[(size_t)r * IND + j] = f2bf(v);
            s += v;
        }
        atomicAdd(&colsum[j], s);
    } else {
        int e = (blockIdx.x - VB) * 256 + threadIdx.x;
        if (e < NE) atomicAdd(&counts[ei[NE + e]], 1);
    }
}

// parallel scan, pass 1: per-block exclusive scan + block sums
__global__ __launch_bounds__(256) void scan1_kernel(const int* __restrict__ counts,
                                                    int* __restrict__ row_start,
                                                    int* __restrict__ blocksums) {
    __shared__ int s[256];
    int t = threadIdx.x, i = blockIdx.x * 256 + t;
    int v = (i < NN) ? counts[i] : 0;
    s[t] = v;
    __syncthreads();
    for (int off = 1; off < 256; off <<= 1) {
        int u = (t >= off) ? s[t - off] : 0;
        __syncthreads();
        s[t] += u;
        __syncthreads();
    }
    if (i < NN) row_start[i] = s[t] - v;      // local exclusive
    if (t == 255) blocksums[blockIdx.x] = s[255];
}

// pass 2 (block 0) + weight conversion (blocks 1..545)
__global__ __launch_bounds__(256) void scan2conv(const int* __restrict__ blocksums,
                                                 int* __restrict__ blockoffs,
                                                 const float* __restrict__ W0,
                                                 const float* __restrict__ W1,
                                                 const float* __restrict__ W2,
                                                 const float* __restrict__ Wout,
                                                 ushort* __restrict__ Wt0,
                                                 ushort* __restrict__ Wt1,
                                                 ushort* __restrict__ Wt2,
                                                 ushort* __restrict__ Wto,
                                                 const float* __restrict__ colsum,
                                                 ushort* __restrict__ Xv) {
    int t = threadIdx.x;
    if (blockIdx.x == 0) {
        __shared__ int s[256];
        int v = (t < NBLK) ? blocksums[t] : 0;
        s[t] = v;
        __syncthreads();
        for (int off = 1; off < 256; off <<= 1) {
            int u = (t >= off) ? s[t - off] : 0;
            __syncthreads();
            s[t] += u;
            __syncthreads();
        }
        if (t < NBLK) blockoffs[t] = s[t] - v;    // exclusive
        return;
    }
    int bid = blockIdx.x - 1;
    if (bid < 256) {               // W0: [256][256] -> Wt0 [256][256]
        int idx = bid * 256 + t;
        int k = idx >> 8, n = idx & 255;
        Wt0[n * IND + k] = f2bf(W0[idx]);
    } else if (bid < 384) {        // W1: [128][256] -> Wt1 [256][128]
        int idx = (bid - 256) * 256 + t;
        int k = idx >> 8, n = idx & 255;
        Wt1[n * HD + k] = f2bf(W1[idx]);
    } else if (bid < 512) {        // W2
        int idx = (bid - 384) * 256 + t;
        int k = idx >> 8, n = idx & 255;
        Wt2[n * HD + k] = f2bf(W2[idx]);
    } else if (bid < 544) {        // Wout: [128][64] -> Wto [64][128]
        int idx = (bid - 512) * 256 + t;
        int k = idx >> 6, n = idx & 63;
        Wto[n * HD + k] = f2bf(Wout[idx]);
    } else {                       // virtual node row
        Xv[(size_t)NN * IND + t] = f2bf(colsum[t] * (1.0f / NN));
    }
}

// pass 3: add block offsets, init cursor, set row_start[NN]
__global__ __launch_bounds__(256) void scan3_kernel(int* __restrict__ row_start,
                                                    const int* __restrict__ blockoffs,
                                                    int* __restrict__ cursor) {
    int i = blockIdx.x * 256 + threadIdx.x;
    if (i < NN) {
        int r = row_start[i] + blockoffs[blockIdx.x];
        row_start[i] = r;
        cursor[i]    = r;
    }
    if (i == 0) row_start[NN] = NE;
}

__global__ __launch_bounds__(256) void fill_kernel(const int* __restrict__ ei,
                                                   int* __restrict__ cursor,
                                                   int* __restrict__ csr) {
    int e = blockIdx.x * 256 + threadIdx.x;
    if (e < NE) {
        int d   = ei[NE + e];
        int pos = atomicAdd(&cursor[d], 1);
        csr[pos] = ei[e];
    }
}

// ---------------- per-layer kernels ----------------

// H[NV][256](bf16) = A[NV][K](bf16) @ Wt[256][K]^T(bf16), fp32 acc via MFMA.
// B k-slice staged in LDS (16KB) via global_load_lds; A direct global->reg.
// Block = 4 waves (2x2): wave = 32 rows x 128 cols (2x8 16x16 frags).
// Fused: alpha epilogue (wave wc covers exactly head wc); block 0 zeroes vacc/vden.
template <int K>
__global__ __launch_bounds__(256) void gemm_mfma(const ushort* __restrict__ A,
                                                 const ushort* __restrict__ Bt,
                                                 const float* __restrict__ a_s,
                                                 const float* __restrict__ a_d,
                                                 ushort* __restrict__ H,
                                                 float* __restrict__ as_,
                                                 float* __restrict__ ad_,
                                                 float* __restrict__ vacc,
                                                 float* __restrict__ vden) {
    __shared__ ushort Bs[256 * 32];            // [col][32 k] = 16KB
    if (blockIdx.x == 0) {                     // zero virtual-node accumulators
        vacc[threadIdx.x] = 0.f;
        if (threadIdx.x < 2) vden[threadIdx.x] = 0.f;
    }
    const int tid  = threadIdx.x;
    const int wave = tid >> 6, lane = tid & 63;
    const int wr   = wave >> 1, wc = wave & 1;
    const int lrow = lane & 15, lk = lane >> 4;
    const int r0   = blockIdx.x * 64 + wr * 32;

    int ar0 = min(r0 + lrow,      NV - 1);
    int ar1 = min(r0 + 16 + lrow, NV - 1);
    const ushort* Ap0 = A + (size_t)ar0 * K + lk * 8;
    const ushort* Ap1 = A + (size_t)ar1 * K + lk * 8;
    // B staging source: lane l covers col cb + l/4, k-slot l%4
    const int scol  = lane >> 2;
    const int sslot = lane & 3;

    f32x4 acc[2][8] = {};
    for (int k0 = 0; k0 < K; k0 += 32) {
#pragma unroll
        for (int q = 0; q < 4; ++q) {
            int cb = wave * 64 + q * 16;
            gload_lds16(Bt + (size_t)(cb + scol) * K + k0 + sslot * 8, &Bs[cb * 32]);
        }
        short8 a0 = *reinterpret_cast<const short8*>(Ap0 + k0);
        short8 a1 = *reinterpret_cast<const short8*>(Ap1 + k0);
        __syncthreads();                       // drains global_load_lds (vmcnt 0)
#pragma unroll
        for (int n = 0; n < 8; ++n) {
            short8 bf = *reinterpret_cast<const short8*>(&Bs[(wc * 128 + n * 16 + lrow) * 32 + lk * 8]);
            acc[0][n] = __builtin_amdgcn_mfma_f32_16x16x32_bf16(a0, bf, acc[0][n], 0, 0, 0);
            acc[1][n] = __builtin_amdgcn_mfma_f32_16x16x32_bf16(a1, bf, acc[1][n], 0, 0, 0);
        }
        __syncthreads();
    }

    // C/D layout: col = wc*128 + n*16 + lrow, row = r0 + m*16 + lk*4 + r
#pragma unroll
    for (int m = 0; m < 2; ++m)
#pragma unroll
        for (int n = 0; n < 8; ++n) {
            int c = wc * 128 + n * 16 + lrow;
#pragma unroll
            for (int r = 0; r < 4; ++r) {
                int row = r0 + m * 16 + lk * 4 + r;
                if (row < NV) H[(size_t)row * NHC + c] = f2bf(acc[m][n][r]);
            }
        }

    // fused alpha for head wc: coef flat index = wc*128 + col_within_head
    float cs[8], cd[8];
#pragma unroll
    for (int n = 0; n < 8; ++n) {
        cs[n] = a_s[wc * 128 + n * 16 + lrow];
        cd[n] = a_d[wc * 128 + n * 16 + lrow];
    }
#pragma unroll
    for (int m = 0; m < 2; ++m)
#pragma unroll
        for (int r = 0; r < 4; ++r) {
            float s = 0.f, d = 0.f;
#pragma unroll
            for (int n = 0; n < 8; ++n) {
                s += acc[m][n][r] * cs[n];
                d += acc[m][n][r] * cd[n];
            }
            for (int off = 1; off < 16; off <<= 1) {
                s += __shfl_xor(s, off);
                d += __shfl_xor(d, off);
            }
            int row = r0 + m * 16 + lk * 4 + r;
            if (lrow == 0 && row < NV) {
                as_[row * 2 + wc] = s;
                ad_[row * 2 + wc] = d;
            }
        }
}

// weighted sum over all NV rows into vacc[256], denom into vden[2].
// Per-row weights computed once into LDS (no max subtraction; e bounded).
__global__ __launch_bounds__(256) void vsum_kernel(const float* __restrict__ as_,
                                                   const float* __restrict__ ad_,
                                                   const ushort* __restrict__ H,
                                                   float* __restrict__ vden,
                                                   float* __restrict__ vacc) {
    __shared__ float w0s[64], w1s[64];
    int j = threadIdx.x, h = j >> 7;
    int r0 = blockIdx.x * 64;
    if (j < 64) {
        int r = r0 + j;
        float p0 = 0.f, p1 = 0.f;
        if (r < NV) {
            float2 adv = *reinterpret_cast<const float2*>(ad_ + 2 * NN);
            float2 asv = *reinterpret_cast<const float2*>(as_ + 2 * r);
            p0 = __expf(lrelu(asv.x + adv.x));
            p1 = __expf(lrelu(asv.y + adv.y));
        }
        w0s[j] = p0; w1s[j] = p1;
    }
    __syncthreads();
    int re = min(r0 + 64, NV) - r0;
    float acc = 0.f, dsum = 0.f;
    for (int rr = 0; rr < re; ++rr) {
        float w = h ? w1s[rr] : w0s[rr];
        acc += w * bf2f(H[(size_t)(r0 + rr) * NHC + j]);
        dsum += w;
    }
    atomicAdd(&vacc[j], acc);
    if ((j & 127) == 0) atomicAdd(&vden[h], dsum);
}

// regular nodes: one wave per dst node. Unnormalized Σ p·H[src]; per-lane
// weight precompute, v_readlane broadcast (j is wave-uniform), 4-wide
// unrolled gathers for MLP. Lane covers 4 cols of one head (ushort4);
// head-mean via shfl_xor(32). Virtual node (i==NN) reads vacc/vden.
// LN + gelu fused.
__global__ __launch_bounds__(256) void node_kernel(const int* __restrict__ row_start,
                                                   const int* __restrict__ csr,
                                                   const float* __restrict__ as_,
                                                   const float* __restrict__ ad_,
                                                   const ushort* __restrict__ H,
                                                   const float* __restrict__ vacc,
                                                   const float* __restrict__ vden,
                                                   const float* __restrict__ b,
                                                   const float* __restrict__ g,
                                                   const float* __restrict__ be,
                                                   ushort* __restrict__ hn) {
    int wave = threadIdx.x >> 6, lane = threadIdx.x & 63;
    int i = blockIdx.x * 4 + wave;
    if (i > NN) return;
    int  l5 = lane & 31;
    bool h0 = lane < 32;

    float acc0 = 0.f, acc1 = 0.f, acc2 = 0.f, acc3 = 0.f, dp;
    if (i == NN) {
        int base = (h0 ? 0 : 128) + 4 * l5;
        acc0 = vacc[base];     acc1 = vacc[base + 1];
        acc2 = vacc[base + 2]; acc3 = vacc[base + 3];
        dp = vden[h0 ? 0 : 1];
    } else {
        int rs = row_start[i], cnt = row_start[i + 1] - rs;
        int tot = cnt + 2; // + virtual, + self
        float2 adv = *reinterpret_cast<const float2*>(ad_ + 2 * i);
        float dp0 = 0.f, dp1 = 0.f;
        const ushort4* H4 = reinterpret_cast<const ushort4*>(H);
        for (int bse = 0; bse < tot; bse += 64) {
            int idx = bse + lane;
            int src_l = 0; float p0_l = 0.f, p1_l = 0.f;
            if (idx < tot) {
                src_l = idx < cnt ? csr[rs + idx] : (idx == cnt ? NN : i);
                float2 asv = *reinterpret_cast<const float2*>(as_ + 2 * src_l);
                p0_l = __expf(lrelu(asv.x + adv.x));
                p1_l = __expf(lrelu(asv.y + adv.y));
                dp0 += p0_l; dp1 += p1_l;
            }
            int chunk = min(64, tot - bse);
            int j = 0;
            for (; j + 4 <= chunk; j += 4) {
                int sA = __builtin_amdgcn_readlane(src_l, j);
                int sB = __builtin_amdgcn_readlane(src_l, j + 1);
                int sC = __builtin_amdgcn_readlane(src_l, j + 2);
                int sD = __builtin_amdgcn_readlane(src_l, j + 3);
                ushort4 qA = H4[(size_t)sA * 64 + lane];
                ushort4 qB = H4[(size_t)sB * 64 + lane];
                ushort4 qC = H4[(size_t)sC * 64 + lane];
                ushort4 qD = H4[(size_t)sD * 64 + lane];
                float wA = h0 ? rlane_f(p0_l, j)     : rlane_f(p1_l, j);
                float wB = h0 ? rlane_f(p0_l, j + 1) : rlane_f(p1_l, j + 1);
                float wC = h0 ? rlane_f(p0_l, j + 2) : rlane_f(p1_l, j + 2);
                float wD = h0 ? rlane_f(p0_l, j + 3) : rlane_f(p1_l, j + 3);
                acc0 += wA * bf2f(qA.x); acc1 += wA * bf2f(qA.y);
                acc2 += wA * bf2f(qA.z); acc3 += wA * bf2f(qA.w);
                acc0 += wB * bf2f(qB.x); acc1 += wB * bf2f(qB.y);
                acc2 += wB * bf2f(qB.z); acc3 += wB * bf2f(qB.w);
                acc0 += wC * bf2f(qC.x); acc1 += wC * bf2f(qC.y);
                acc2 += wC * bf2f(qC.z); acc3 += wC * bf2f(qC.w);
                acc0 += wD * bf2f(qD.x); acc1 += wD * bf2f(qD.y);
                acc2 += wD * bf2f(qD.z); acc3 += wD * bf2f(qD.w);
            }
            for (; j < chunk; ++j) {
                int   s = __builtin_amdgcn_readlane(src_l, j);
                ushort4 q = H4[(size_t)s * 64 + lane];
                float w = h0 ? rlane_f(p0_l, j) : rlane_f(p1_l, j);
                acc0 += w * bf2f(q.x); acc1 += w * bf2f(q.y);
                acc2 += w * bf2f(q.z); acc3 += w * bf2f(q.w);
            }
        }
        for (int off = 32; off; off >>= 1) {
            dp0 += __shfl_xor(dp0, off);
            dp1 += __shfl_xor(dp1, off);
        }
        dp = h0 ? dp0 : dp1;
    }

    float r = 1.f / (dp + 1e-16f);
    float4 bv = reinterpret_cast<const float4*>(b)[l5];
    float z0 = acc0 * r, z1 = acc1 * r, z2 = acc2 * r, z3 = acc3 * r;
    float y0 = 0.5f * (z0 + __shfl_xor(z0, 32)) + bv.x;
    float y1 = 0.5f * (z1 + __shfl_xor(z1, 32)) + bv.y;
    float y2 = 0.5f * (z2 + __shfl_xor(z2, 32)) + bv.z;
    float y3 = 0.5f * (z3 + __shfl_xor(z3, 32)) + bv.w;
    // LN over 128 dims; each dim appears twice across the wave -> /256
    float s = y0 + y1 + y2 + y3;
    for (int off = 32; off; off >>= 1) s += __shfl_xor(s, off);
    float mu = s * (1.f / 256.f);
    float c0 = y0 - mu, c1 = y1 - mu, c2 = y2 - mu, c3 = y3 - mu;
    float v = c0 * c0 + c1 * c1 + c2 * c2 + c3 * c3;
    for (int off = 32; off; off >>= 1) v += __shfl_xor(v, off);
    float rstd = rsqrtf(v * (1.f / 256.f) + 1e-5f);
    if (h0) {
        float4 gv  = reinterpret_cast<const float4*>(g)[l5];
        float4 bev = reinterpret_cast<const float4*>(be)[l5];
        ushort4 o;
        o.x = f2bf(gelu(c0 * rstd * gv.x + bev.x));
        o.y = f2bf(gelu(c1 * rstd * gv.y + bev.y));
        o.z = f2bf(gelu(c2 * rstd * gv.z + bev.z));
        o.w = f2bf(gelu(c3 * rstd * gv.w + bev.w));
        *reinterpret_cast<ushort4*>(&hn[(size_t)i * HD + 4 * l5]) = o;
    }
}

// out[NN][64] = h[NN][128](bf16) @ Wto[64][128]^T(bf16) + bout, via MFMA.
// B k-slice (64x32 = 4KB) staged in LDS; block = 4 waves x 32 rows = 128 rows.
__global__ __launch_bounds__(256) void out_mfma(const ushort* __restrict__ A,
                                                const ushort* __restrict__ Bt,
                                                const float* __restrict__ bout,
                                                float* __restrict__ out) {
    __shared__ ushort Bs[64 * 32];             // 4KB
    const int tid  = threadIdx.x;
    const int wave = tid >> 6, lane = tid & 63;
    const int lrow = lane & 15, lk = lane >> 4;
    const int r0   = blockIdx.x * 128 + wave * 32;

    int ar0 = min(r0 + lrow,      NN - 1);
    int ar1 = min(r0 + 16 + lrow, NN - 1);
    const ushort* Ap0 = A + (size_t)ar0 * HD + lk * 8;
    const ushort* Ap1 = A + (size_t)ar1 * HD + lk * 8;
    const int scol  = lane >> 2;
    const int sslot = lane & 3;

    f32x4 acc[2][4] = {};
#pragma unroll
    for (int k0 = 0; k0 < HD; k0 += 32) {
        int cb = wave * 16;                    // each wave stages 16 cols
        gload_lds16(Bt + (size_t)(cb + scol) * HD + k0 + sslot * 8, &Bs[cb * 32]);
        short8 a0 = *reinterpret_cast<const short8*>(Ap0 + k0);
        short8 a1 = *reinterpret_cast<const short8*>(Ap1 + k0);
        __syncthreads();
#pragma unroll
        for (int n = 0; n < 4; ++n) {
            short8 bf = *reinterpret_cast<const short8*>(&Bs[(n * 16 + lrow) * 32 + lk * 8]);
            acc[0][n] = __builtin_amdgcn_mfma_f32_16x16x32_bf16(a0, bf, acc[0][n], 0, 0, 0);
            acc[1][n] = __builtin_amdgcn_mfma_f32_16x16x32_bf16(a1, bf, acc[1][n], 0, 0, 0);
        }
        __syncthreads();
    }
#pragma unroll
    for (int m = 0; m < 2; ++m)
#pragma unroll
        for (int n = 0; n < 4; ++n) {
            int c = n * 16 + lrow;
            float bc = bout[c];
#pragma unroll
            for (int r = 0; r < 4; ++r) {
                int row = r0 + m * 16 + lk * 4 + r;
                if (row < NN) out[(size_t)row * 64 + c] = acc[m][n][r] + bc;
            }
        }
}

// ---------------- launcher ----------------

extern "C" void kernel_launch(void* const* d_in, const int* in_sizes, int n_in,
                              void* d_out, int out_size, void* d_ws, size_t ws_size,
                              hipStream_t stream) {
    (void)in_sizes; (void)n_in; (void)out_size; (void)ws_size;

    const float* X  = (const float*)d_in[0];
    const int*   ei = (const int*)d_in[1];
    const float* W[3]   = {(const float*)d_in[3],  (const float*)d_in[9],  (const float*)d_in[15]};
    const float* Asp[3] = {(const float*)d_in[4],  (const float*)d_in[10], (const float*)d_in[16]};
    const float* Adp[3] = {(const float*)d_in[5],  (const float*)d_in[11], (const float*)d_in[17]};
    const float* Bb[3]  = {(const float*)d_in[6],  (const float*)d_in[12], (const float*)d_in[18]};
    const float* Gg[3]  = {(const float*)d_in[7],  (const float*)d_in[13], (const float*)d_in[19]};
    const float* Be[3]  = {(const float*)d_in[8],  (const float*)d_in[14], (const float*)d_in[20]};
    const float* Wout = (const float*)d_in[21];
    const float* bout = (const float*)d_in[22];
    float* out = (float*)d_out;

    uintptr_t base = (uintptr_t)d_ws;
    auto take = [&](size_t bytes) {
        uintptr_t p = base;
        base += (bytes + 255) & ~(size_t)255;
        return p;
    };
    ushort* Xv    = (ushort*)take((size_t)NV * IND * 2);
    ushort* Hbuf  = (ushort*)take((size_t)NV * NHC * 2);
    ushort* hA    = (ushort*)take((size_t)NV * HD * 2);
    ushort* hB    = (ushort*)take((size_t)NV * HD * 2);
    ushort* Wt0   = (ushort*)take((size_t)256 * IND * 2);
    ushort* Wt1   = (ushort*)take((size_t)256 * HD * 2);
    ushort* Wt2   = (ushort*)take((size_t)256 * HD * 2);
    ushort* Wto   = (ushort*)take((size_t)64 * HD * 2);
    float* as_    = (float*)take((size_t)NV * 2 * 4);
    float* ad_    = (float*)take((size_t)NV * 2 * 4);
    float* colsum = (float*)take(256 * 4);
    int*   counts = (int*)take((size_t)NN * 4);
    int*   rowst  = (int*)take((size_t)(NN + 1) * 4);
    int*   cursor = (int*)take((size_t)NN * 4);
    int*   csr    = (int*)take((size_t)NE * 4);
    int*   bsums  = (int*)take((size_t)NBLK * 4);
    int*   boffs  = (int*)take((size_t)NBLK * 4);
    float* vden   = (float*)take(2 * 4);
    float* vacc   = (float*)take(256 * 4);
    ushort* Wt[3] = {Wt0, Wt1, Wt2};

    // setup
    zero_init<<<196, 256, 0, stream>>>(counts, colsum);
    vnode_count<<<VB + CB, 256, 0, stream>>>(X, Xv, colsum, ei, counts);
    scan1_kernel<<<NBLK, 256, 0, stream>>>(counts, rowst, bsums);
    scan2conv<<<546, 256, 0, stream>>>(bsums, boffs, W[0], W[1], W[2], Wout,
                                       Wt0, Wt1, Wt2, Wto, colsum, Xv);
    scan3_kernel<<<NBLK, 256, 0, stream>>>(rowst, boffs, cursor);
    fill_kernel<<<(NE + 255) / 256, 256, 0, stream>>>(ei, cursor, csr);

    const ushort* hin = Xv;
    ushort* houts[3] = {hA, hB, hA};
    for (int li = 0; li < 3; ++li) {
        if (li == 0)
            gemm_mfma<IND><<<(NV + 63) / 64, 256, 0, stream>>>(hin, Wt[li], Asp[li], Adp[li], Hbuf, as_, ad_, vacc, vden);
        else
            gemm_mfma<HD><<<(NV + 63) / 64, 256, 0, stream>>>(hin, Wt[li], Asp[li], Adp[li], Hbuf, as_, ad_, vacc, vden);
        vsum_kernel<<<(NV + 63) / 64, 256, 0, stream>>>(as_, ad_, Hbuf, vden, vacc);
        node_kernel<<<NN / 4 + 1, 256, 0, stream>>>(rowst, csr, as_, ad_, Hbuf, vacc, vden,
                                                    Bb[li], Gg[li], Be[li], houts[li]);
        hin = houts[li];
    }
    out_mfma<<<(NN + 127) / 128, 256, 0, stream>>>(hin, Wto, bout, out);
}

// Round 8
// 480.882 us; speedup vs baseline: 2.3472x; 1.0889x over previous
//
#include <hip/hip_runtime.h>
#include <cmath>
#include <climits>

#define DEV __device__ __forceinline__

constexpr int NN  = 50000;    // real nodes
constexpr int NE  = 400000;   // regular edges
constexpr int NV  = NN + 1;   // + virtual node
constexpr int IND = 256;      // input dim
constexpr int HD  = 128;      // hidden dim
constexpr int NHC = 256;      // heads * hidden = GEMM N
constexpr int NBLK = (NN + 255) / 256;   // 196 scan blocks
constexpr int VB2  = (NN + 127) / 128;   // 391 vnode blocks (128 rows each)
constexpr int CB2  = (NE + 1023) / 1024; // 391 histogram blocks (4 edges/thread)

typedef short short8 __attribute__((ext_vector_type(8)));
typedef float f32x4  __attribute__((ext_vector_type(4)));

DEV float lrelu(float x) { return x > 0.f ? x : 0.2f * x; }
DEV float gelu(float x)  { return x * 0.5f * (1.f + erff(x * 0.70710678118654752f)); }
// bf16 storage as ushort; RNE convert
DEV ushort f2bf(float f) { uint u = __float_as_uint(f); return (ushort)((u + 0x7FFFu + ((u >> 16) & 1u)) >> 16); }
DEV float  bf2f(ushort h) { return __uint_as_float((uint)h << 16); }
// wave-uniform lane broadcast via v_readlane (no LDS pipe)
DEV float rlane_f(float v, int j) { return __uint_as_float(__builtin_amdgcn_readlane(__float_as_uint(v), j)); }

// async global->LDS, 16B per lane; dest = lds + lane*16 (wave-uniform base)
DEV void gload_lds16(const ushort* g, ushort* l) {
    __builtin_amdgcn_global_load_lds(
        (const __attribute__((address_space(1))) void*)g,
        (__attribute__((address_space(3))) void*)l,
        16, 0, 0);
}

// ---------------- setup kernels ----------------

// fused: blocks [0,VB2): copy X -> Xv (bf16, float4/ushort4) + column sums;
//        blocks [VB2, VB2+CB2): edge dst histogram (int4)
__global__ __launch_bounds__(256) void vnode_count(const float* __restrict__ X,
                                                   ushort* __restrict__ Xv,
                                                   float* __restrict__ colsum,
                                                   const int* __restrict__ ei,
                                                   int* __restrict__ counts) {
    if (blockIdx.x < VB2) {
        __shared__ float cpart[4][256];
        int t = threadIdx.x;
        int w = t >> 6, l = t & 63;
        int r0 = blockIdx.x * 128 + w * 32;
        const float4* X4 = reinterpret_cast<const float4*>(X);
        ushort4*      Xv4 = reinterpret_cast<ushort4*>(Xv);
        float s0 = 0.f, s1 = 0.f, s2 = 0.f, s3 = 0.f;
        int rend = min(r0 + 32, NN);
        for (int r = r0; r < rend; ++r) {
            float4 v = X4[(size_t)r * 64 + l];
            ushort4 o = {f2bf(v.x), f2bf(v.y), f2bf(v.z), f2bf(v.w)};
            Xv4[(size_t)r * 64 + l] = o;
            s0 += v.x; s1 += v.y; s2 += v.z; s3 += v.w;
        }
        cpart[w][4 * l]     = s0;
        cpart[w][4 * l + 1] = s1;
        cpart[w][4 * l + 2] = s2;
        cpart[w][4 * l + 3] = s3;
        __syncthreads();
        float tot = cpart[0][t] + cpart[1][t] + cpart[2][t] + cpart[3][t];
        atomicAdd(&colsum[t], tot);
    } else {
        int e4 = (blockIdx.x - VB2) * 1024 + threadIdx.x * 4;
        if (e4 + 3 < NE) {
            int4 d = *reinterpret_cast<const int4*>(ei + NE + e4);
            atomicAdd(&counts[d.x], 1);
            atomicAdd(&counts[d.y], 1);
            atomicAdd(&counts[d.z], 1);
            atomicAdd(&counts[d.w], 1);
        } else {
            for (int j = e4; j < NE; ++j) atomicAdd(&counts[ei[NE + j]], 1);
        }
    }
}

// parallel scan, pass 1: per-block exclusive scan + block sums
__global__ __launch_bounds__(256) void scan1_kernel(const int* __restrict__ counts,
                                                    int* __restrict__ row_start,
                                                    int* __restrict__ blocksums) {
    __shared__ int s[256];
    int t = threadIdx.x, i = blockIdx.x * 256 + t;
    int v = (i < NN) ? counts[i] : 0;
    s[t] = v;
    __syncthreads();
    for (int off = 1; off < 256; off <<= 1) {
        int u = (t >= off) ? s[t - off] : 0;
        __syncthreads();
        s[t] += u;
        __syncthreads();
    }
    if (i < NN) row_start[i] = s[t] - v;      // local exclusive
    if (t == 255) blocksums[blockIdx.x] = s[255];
}

// pass 2 (block 0) + weight conversion (blocks 1..545)
__global__ __launch_bounds__(256) void scan2conv(const int* __restrict__ blocksums,
                                                 int* __restrict__ blockoffs,
                                                 const float* __restrict__ W0,
                                                 const float* __restrict__ W1,
                                                 const float* __restrict__ W2,
                                                 const float* __restrict__ Wout,
                                                 ushort* __restrict__ Wt0,
                                                 ushort* __restrict__ Wt1,
                                                 ushort* __restrict__ Wt2,
                                                 ushort* __restrict__ Wto,
                                                 const float* __restrict__ colsum,
                                                 ushort* __restrict__ Xv) {
    int t = threadIdx.x;
    if (blockIdx.x == 0) {
        __shared__ int s[256];
        int v = (t < NBLK) ? blocksums[t] : 0;
        s[t] = v;
        __syncthreads();
        for (int off = 1; off < 256; off <<= 1) {
            int u = (t >= off) ? s[t - off] : 0;
            __syncthreads();
            s[t] += u;
            __syncthreads();
        }
        if (t < NBLK) blockoffs[t] = s[t] - v;    // exclusive
        return;
    }
    int bid = blockIdx.x - 1;
    if (bid < 256) {               // W0: [256][256] -> Wt0 [256][256]
        int idx = bid * 256 + t;
        int k = idx >> 8, n = idx & 255;
        Wt0[n * IND + k] = f2bf(W0[idx]);
    } else if (bid < 384) {        // W1: [128][256] -> Wt1 [256][128]
        int idx = (bid - 256) * 256 + t;
        int k = idx >> 8, n = idx & 255;
        Wt1[n * HD + k] = f2bf(W1[idx]);
    } else if (bid < 512) {        // W2
        int idx = (bid - 384) * 256 + t;
        int k = idx >> 8, n = idx & 255;
        Wt2[n * HD + k] = f2bf(W2[idx]);
    } else if (bid < 544) {        // Wout: [128][64] -> Wto [64][128]
        int idx = (bid - 512) * 256 + t;
        int k = idx >> 6, n = idx & 63;
        Wto[n * HD + k] = f2bf(Wout[idx]);
    } else {                       // virtual node row
        Xv[(size_t)NN * IND + t] = f2bf(colsum[t] * (1.0f / NN));
    }
}

// pass 3: add block offsets, init cursor, set row_start[NN]
__global__ __launch_bounds__(256) void scan3_kernel(int* __restrict__ row_start,
                                                    const int* __restrict__ blockoffs,
                                                    int* __restrict__ cursor) {
    int i = blockIdx.x * 256 + threadIdx.x;
    if (i < NN) {
        int r = row_start[i] + blockoffs[blockIdx.x];
        row_start[i] = r;
        cursor[i]    = r;
    }
    if (i == 0) row_start[NN] = NE;
}

__global__ __launch_bounds__(256) void fill_kernel(const int* __restrict__ ei,
                                                   int* __restrict__ cursor,
                                                   int* __restrict__ csr) {
    int e = blockIdx.x * 256 + threadIdx.x;
    if (e < NE) {
        int d   = ei[NE + e];
        int pos = atomicAdd(&cursor[d], 1);
        csr[pos] = ei[e];
    }
}

// ---------------- per-layer kernels ----------------

// H[NV][256](bf16) = A[NV][K](bf16) @ Wt[256][K]^T(bf16), fp32 acc via MFMA.
// B k-slice staged in LDS (16KB) via global_load_lds; A direct global->reg.
// Block = 4 waves (2x2): wave = 32 rows x 128 cols (2x8 16x16 frags).
// Fused: alpha epilogue (wave wc covers exactly head wc); block 0 zeroes vacc/vden.
template <int K>
__global__ __launch_bounds__(256) void gemm_mfma(const ushort* __restrict__ A,
                                                 const ushort* __restrict__ Bt,
                                                 const float* __restrict__ a_s,
                                                 const float* __restrict__ a_d,
                                                 ushort* __restrict__ H,
                                                 float* __restrict__ as_,
                                                 float* __restrict__ ad_,
                                                 float* __restrict__ vacc,
                                                 float* __restrict__ vden) {
    __shared__ ushort Bs[256 * 32];            // [col][32 k] = 16KB
    if (blockIdx.x == 0) {                     // zero virtual-node accumulators
        vacc[threadIdx.x] = 0.f;
        if (threadIdx.x < 2) vden[threadIdx.x] = 0.f;
    }
    const int tid  = threadIdx.x;
    const int wave = tid >> 6, lane = tid & 63;
    const int wr   = wave >> 1, wc = wave & 1;
    const int lrow = lane & 15, lk = lane >> 4;
    const int r0   = blockIdx.x * 64 + wr * 32;

    int ar0 = min(r0 + lrow,      NV - 1);
    int ar1 = min(r0 + 16 + lrow, NV - 1);
    const ushort* Ap0 = A + (size_t)ar0 * K + lk * 8;
    const ushort* Ap1 = A + (size_t)ar1 * K + lk * 8;
    // B staging source: lane l covers col cb + l/4, k-slot l%4
    const int scol  = lane >> 2;
    const int sslot = lane & 3;

    f32x4 acc[2][8] = {};
    for (int k0 = 0; k0 < K; k0 += 32) {
#pragma unroll
        for (int q = 0; q < 4; ++q) {
            int cb = wave * 64 + q * 16;
            gload_lds16(Bt + (size_t)(cb + scol) * K + k0 + sslot * 8, &Bs[cb * 32]);
        }
        short8 a0 = *reinterpret_cast<const short8*>(Ap0 + k0);
        short8 a1 = *reinterpret_cast<const short8*>(Ap1 + k0);
        __syncthreads();                       // drains global_load_lds (vmcnt 0)
#pragma unroll
        for (int n = 0; n < 8; ++n) {
            short8 bf = *reinterpret_cast<const short8*>(&Bs[(wc * 128 + n * 16 + lrow) * 32 + lk * 8]);
            acc[0][n] = __builtin_amdgcn_mfma_f32_16x16x32_bf16(a0, bf, acc[0][n], 0, 0, 0);
            acc[1][n] = __builtin_amdgcn_mfma_f32_16x16x32_bf16(a1, bf, acc[1][n], 0, 0, 0);
        }
        __syncthreads();
    }

    // C/D layout: col = wc*128 + n*16 + lrow, row = r0 + m*16 + lk*4 + r
#pragma unroll
    for (int m = 0; m < 2; ++m)
#pragma unroll
        for (int n = 0; n < 8; ++n) {
            int c = wc * 128 + n * 16 + lrow;
#pragma unroll
            for (int r = 0; r < 4; ++r) {
                int row = r0 + m * 16 + lk * 4 + r;
                if (row < NV) H[(size_t)row * NHC + c] = f2bf(acc[m][n][r]);
            }
        }

    // fused alpha for head wc: coef flat index = wc*128 + col_within_head
    float cs[8], cd[8];
#pragma unroll
    for (int n = 0; n < 8; ++n) {
        cs[n] = a_s[wc * 128 + n * 16 + lrow];
        cd[n] = a_d[wc * 128 + n * 16 + lrow];
    }
#pragma unroll
    for (int m = 0; m < 2; ++m)
#pragma unroll
        for (int r = 0; r < 4; ++r) {
            float s = 0.f, d = 0.f;
#pragma unroll
            for (int n = 0; n < 8; ++n) {
                s += acc[m][n][r] * cs[n];
                d += acc[m][n][r] * cd[n];
            }
            for (int off = 1; off < 16; off <<= 1) {
                s += __shfl_xor(s, off);
                d += __shfl_xor(d, off);
            }
            int row = r0 + m * 16 + lk * 4 + r;
            if (lrow == 0 && row < NV) {
                as_[row * 2 + wc] = s;
                ad_[row * 2 + wc] = d;
            }
        }
}

// weighted sum over all NV rows into vacc[256], denom into vden[2].
// Vectorized: wave w handles 16 rows, lane covers 4 cols (ushort4 loads);
// cross-wave LDS reduce -> 256 atomics/block. No max subtraction (e bounded).
__global__ __launch_bounds__(256) void vsum_kernel(const float* __restrict__ as_,
                                                   const float* __restrict__ ad_,
                                                   const ushort* __restrict__ H,
                                                   float* __restrict__ vden,
                                                   float* __restrict__ vacc) {
    __shared__ float w0s[64], w1s[64];
    __shared__ float part[4][256];
    int t = threadIdx.x;
    int w = t >> 6, l = t & 63;
    int r0 = blockIdx.x * 64;
    if (t < 64) {
        int r = r0 + t;
        float p0 = 0.f, p1 = 0.f;
        if (r < NV) {
            float2 adv = *reinterpret_cast<const float2*>(ad_ + 2 * NN);
            float2 asv = *reinterpret_cast<const float2*>(as_ + 2 * r);
            p0 = __expf(lrelu(asv.x + adv.x));
            p1 = __expf(lrelu(asv.y + adv.y));
        }
        w0s[t] = p0; w1s[t] = p1;
    }
    __syncthreads();
    const ushort4* H4 = reinterpret_cast<const ushort4*>(H);
    bool h0 = l < 32;
    float a0 = 0.f, a1 = 0.f, a2 = 0.f, a3 = 0.f;
    int rbase = r0 + w * 16;
#pragma unroll 4
    for (int it = 0; it < 16; ++it) {
        int r = rbase + it;
        if (r < NV) {
            float wt = h0 ? w0s[w * 16 + it] : w1s[w * 16 + it];
            ushort4 q = H4[(size_t)r * 64 + l];
            a0 += wt * bf2f(q.x); a1 += wt * bf2f(q.y);
            a2 += wt * bf2f(q.z); a3 += wt * bf2f(q.w);
        }
    }
    part[w][4 * l]     = a0;
    part[w][4 * l + 1] = a1;
    part[w][4 * l + 2] = a2;
    part[w][4 * l + 3] = a3;
    __syncthreads();
    float tot = part[0][t] + part[1][t] + part[2][t] + part[3][t];
    atomicAdd(&vacc[t], tot);
    if (t < 2) {
        const float* ws = t ? w1s : w0s;
        float d = 0.f;
        for (int j = 0; j < 64; ++j) d += ws[j];
        atomicAdd(&vden[t], d);
    }
}

// regular nodes: one wave per dst node. Unnormalized Σ p·H[src]; per-lane
// weight precompute, v_readlane broadcast (j is wave-uniform), 4-wide
// unrolled gathers for MLP. Lane covers 4 cols of one head (ushort4);
// head-mean via shfl_xor(32). Virtual node (i==NN) reads vacc/vden.
// LN + gelu fused.
__global__ __launch_bounds__(256) void node_kernel(const int* __restrict__ row_start,
                                                   const int* __restrict__ csr,
                                                   const float* __restrict__ as_,
                                                   const float* __restrict__ ad_,
                                                   const ushort* __restrict__ H,
                                                   const float* __restrict__ vacc,
                                                   const float* __restrict__ vden,
                                                   const float* __restrict__ b,
                                                   const float* __restrict__ g,
                                                   const float* __restrict__ be,
                                                   ushort* __restrict__ hn) {
    int wave = threadIdx.x >> 6, lane = threadIdx.x & 63;
    int i = blockIdx.x * 4 + wave;
    if (i > NN) return;
    int  l5 = lane & 31;
    bool h0 = lane < 32;

    float acc0 = 0.f, acc1 = 0.f, acc2 = 0.f, acc3 = 0.f, dp;
    if (i == NN) {
        int base = (h0 ? 0 : 128) + 4 * l5;
        acc0 = vacc[base];     acc1 = vacc[base + 1];
        acc2 = vacc[base + 2]; acc3 = vacc[base + 3];
        dp = vden[h0 ? 0 : 1];
    } else {
        int rs = row_start[i], cnt = row_start[i + 1] - rs;
        int tot = cnt + 2; // + virtual, + self
        float2 adv = *reinterpret_cast<const float2*>(ad_ + 2 * i);
        float dp0 = 0.f, dp1 = 0.f;
        const ushort4* H4 = reinterpret_cast<const ushort4*>(H);
        for (int bse = 0; bse < tot; bse += 64) {
            int idx = bse + lane;
            int src_l = 0; float p0_l = 0.f, p1_l = 0.f;
            if (idx < tot) {
                src_l = idx < cnt ? csr[rs + idx] : (idx == cnt ? NN : i);
                float2 asv = *reinterpret_cast<const float2*>(as_ + 2 * src_l);
                p0_l = __expf(lrelu(asv.x + adv.x));
                p1_l = __expf(lrelu(asv.y + adv.y));
                dp0 += p0_l; dp1 += p1_l;
            }
            int chunk = min(64, tot - bse);
            int j = 0;
            for (; j + 4 <= chunk; j += 4) {
                int sA = __builtin_amdgcn_readlane(src_l, j);
                int sB = __builtin_amdgcn_readlane(src_l, j + 1);
                int sC = __builtin_amdgcn_readlane(src_l, j + 2);
                int sD = __builtin_amdgcn_readlane(src_l, j + 3);
                ushort4 qA = H4[(size_t)sA * 64 + lane];
                ushort4 qB = H4[(size_t)sB * 64 + lane];
                ushort4 qC = H4[(size_t)sC * 64 + lane];
                ushort4 qD = H4[(size_t)sD * 64 + lane];
                float wA = h0 ? rlane_f(p0_l, j)     : rlane_f(p1_l, j);
                float wB = h0 ? rlane_f(p0_l, j + 1) : rlane_f(p1_l, j + 1);
                float wC = h0 ? rlane_f(p0_l, j + 2) : rlane_f(p1_l, j + 2);
                float wD = h0 ? rlane_f(p0_l, j + 3) : rlane_f(p1_l, j + 3);
                acc0 += wA * bf2f(qA.x); acc1 += wA * bf2f(qA.y);
                acc2 += wA * bf2f(qA.z); acc3 += wA * bf2f(qA.w);
                acc0 += wB * bf2f(qB.x); acc1 += wB * bf2f(qB.y);
                acc2 += wB * bf2f(qB.z); acc3 += wB * bf2f(qB.w);
                acc0 += wC * bf2f(qC.x); acc1 += wC * bf2f(qC.y);
                acc2 += wC * bf2f(qC.z); acc3 += wC * bf2f(qC.w);
                acc0 += wD * bf2f(qD.x); acc1 += wD * bf2f(qD.y);
                acc2 += wD * bf2f(qD.z); acc3 += wD * bf2f(qD.w);
            }
            for (; j < chunk; ++j) {
                int   s = __builtin_amdgcn_readlane(src_l, j);
                ushort4 q = H4[(size_t)s * 64 + lane];
                float w = h0 ? rlane_f(p0_l, j) : rlane_f(p1_l, j);
                acc0 += w * bf2f(q.x); acc1 += w * bf2f(q.y);
                acc2 += w * bf2f(q.z); acc3 += w * bf2f(q.w);
            }
        }
        for (int off = 32; off; off >>= 1) {
            dp0 += __shfl_xor(dp0, off);
            dp1 += __shfl_xor(dp1, off);
        }
        dp = h0 ? dp0 : dp1;
    }

    float r = 1.f / (dp + 1e-16f);
    float4 bv = reinterpret_cast<const float4*>(b)[l5];
    float z0 = acc0 * r, z1 = acc1 * r, z2 = acc2 * r, z3 = acc3 * r;
    float y0 = 0.5f * (z0 + __shfl_xor(z0, 32)) + bv.x;
    float y1 = 0.5f * (z1 + __shfl_xor(z1, 32)) + bv.y;
    float y2 = 0.5f * (z2 + __shfl_xor(z2, 32)) + bv.z;
    float y3 = 0.5f * (z3 + __shfl_xor(z3, 32)) + bv.w;
    // LN over 128 dims; each dim appears twice across the wave -> /256
    float s = y0 + y1 + y2 + y3;
    for (int off = 32; off; off >>= 1) s += __shfl_xor(s, off);
    float mu = s * (1.f / 256.f);
    float c0 = y0 - mu, c1 = y1 - mu, c2 = y2 - mu, c3 = y3 - mu;
    float v = c0 * c0 + c1 * c1 + c2 * c2 + c3 * c3;
    for (int off = 32; off; off >>= 1) v += __shfl_xor(v, off);
    float rstd = rsqrtf(v * (1.f / 256.f) + 1e-5f);
    if (h0) {
        float4 gv  = reinterpret_cast<const float4*>(g)[l5];
        float4 bev = reinterpret_cast<const float4*>(be)[l5];
        ushort4 o;
        o.x = f2bf(gelu(c0 * rstd * gv.x + bev.x));
        o.y = f2bf(gelu(c1 * rstd * gv.y + bev.y));
        o.z = f2bf(gelu(c2 * rstd * gv.z + bev.z));
        o.w = f2bf(gelu(c3 * rstd * gv.w + bev.w));
        *reinterpret_cast<ushort4*>(&hn[(size_t)i * HD + 4 * l5]) = o;
    }
}

// out[NN][64] = h[NN][128](bf16) @ Wto[64][128]^T(bf16) + bout, via MFMA.
// B k-slice (64x32 = 4KB) staged in LDS; block = 4 waves x 32 rows = 128 rows.
__global__ __launch_bounds__(256) void out_mfma(const ushort* __restrict__ A,
                                                const ushort* __restrict__ Bt,
                                                const float* __restrict__ bout,
                                                float* __restrict__ out) {
    __shared__ ushort Bs[64 * 32];             // 4KB
    const int tid  = threadIdx.x;
    const int wave = tid >> 6, lane = tid & 63;
    const int lrow = lane & 15, lk = lane >> 4;
    const int r0   = blockIdx.x * 128 + wave * 32;

    int ar0 = min(r0 + lrow,      NN - 1);
    int ar1 = min(r0 + 16 + lrow, NN - 1);
    const ushort* Ap0 = A + (size_t)ar0 * HD + lk * 8;
    const ushort* Ap1 = A + (size_t)ar1 * HD + lk * 8;
    const int scol  = lane >> 2;
    const int sslot = lane & 3;

    f32x4 acc[2][4] = {};
#pragma unroll
    for (int k0 = 0; k0 < HD; k0 += 32) {
        int cb = wave * 16;                    // each wave stages 16 cols
        gload_lds16(Bt + (size_t)(cb + scol) * HD + k0 + sslot * 8, &Bs[cb * 32]);
        short8 a0 = *reinterpret_cast<const short8*>(Ap0 + k0);
        short8 a1 = *reinterpret_cast<const short8*>(Ap1 + k0);
        __syncthreads();
#pragma unroll
        for (int n = 0; n < 4; ++n) {
            short8 bf = *reinterpret_cast<const short8*>(&Bs[(n * 16 + lrow) * 32 + lk * 8]);
            acc[0][n] = __builtin_amdgcn_mfma_f32_16x16x32_bf16(a0, bf, acc[0][n], 0, 0, 0);
            acc[1][n] = __builtin_amdgcn_mfma_f32_16x16x32_bf16(a1, bf, acc[1][n], 0, 0, 0);
        }
        __syncthreads();
    }
#pragma unroll
    for (int m = 0; m < 2; ++m)
#pragma unroll
        for (int n = 0; n < 4; ++n) {
            int c = n * 16 + lrow;
            float bc = bout[c];
#pragma unroll
            for (int r = 0; r < 4; ++r) {
                int row = r0 + m * 16 + lk * 4 + r;
                if (row < NN) out[(size_t)row * 64 + c] = acc[m][n][r] + bc;
            }
        }
}

// ---------------- launcher ----------------

extern "C" void kernel_launch(void* const* d_in, const int* in_sizes, int n_in,
                              void* d_out, int out_size, void* d_ws, size_t ws_size,
                              hipStream_t stream) {
    (void)in_sizes; (void)n_in; (void)out_size; (void)ws_size;

    const float* X  = (const float*)d_in[0];
    const int*   ei = (const int*)d_in[1];
    const float* W[3]   = {(const float*)d_in[3],  (const float*)d_in[9],  (const float*)d_in[15]};
    const float* Asp[3] = {(const float*)d_in[4],  (const float*)d_in[10], (const float*)d_in[16]};
    const float* Adp[3] = {(const float*)d_in[5],  (const float*)d_in[11], (const float*)d_in[17]};
    const float* Bb[3]  = {(const float*)d_in[6],  (const float*)d_in[12], (const float*)d_in[18]};
    const float* Gg[3]  = {(const float*)d_in[7],  (const float*)d_in[13], (const float*)d_in[19]};
    const float* Be[3]  = {(const float*)d_in[8],  (const float*)d_in[14], (const float*)d_in[20]};
    const float* Wout = (const float*)d_in[21];
    const float* bout = (const float*)d_in[22];
    float* out = (float*)d_out;

    uintptr_t base = (uintptr_t)d_ws;
    auto take = [&](size_t bytes) {
        uintptr_t p = base;
        base += (bytes + 255) & ~(size_t)255;
        return p;
    };
    ushort* Xv    = (ushort*)take((size_t)NV * IND * 2);
    ushort* Hbuf  = (ushort*)take((size_t)NV * NHC * 2);
    ushort* hA    = (ushort*)take((size_t)NV * HD * 2);
    ushort* hB    = (ushort*)take((size_t)NV * HD * 2);
    ushort* Wt0   = (ushort*)take((size_t)256 * IND * 2);
    ushort* Wt1   = (ushort*)take((size_t)256 * HD * 2);
    ushort* Wt2   = (ushort*)take((size_t)256 * HD * 2);
    ushort* Wto   = (ushort*)take((size_t)64 * HD * 2);
    float* as_    = (float*)take((size_t)NV * 2 * 4);
    float* ad_    = (float*)take((size_t)NV * 2 * 4);
    float* colsum = (float*)take(256 * 4);
    int*   counts = (int*)take((size_t)NN * 4);
    int*   rowst  = (int*)take((size_t)(NN + 1) * 4);
    int*   cursor = (int*)take((size_t)NN * 4);
    int*   csr    = (int*)take((size_t)NE * 4);
    int*   bsums  = (int*)take((size_t)NBLK * 4);
    int*   boffs  = (int*)take((size_t)NBLK * 4);
    float* vden   = (float*)take(2 * 4);
    float* vacc   = (float*)take(256 * 4);
    ushort* Wt[3] = {Wt0, Wt1, Wt2};

    // setup: zero counts + colsum via memset (graph-capturable)
    hipMemsetAsync(counts, 0, (size_t)NN * 4, stream);
    hipMemsetAsync(colsum, 0, 256 * 4, stream);
    vnode_count<<<VB2 + CB2, 256, 0, stream>>>(X, Xv, colsum, ei, counts);
    scan1_kernel<<<NBLK, 256, 0, stream>>>(counts, rowst, bsums);
    scan2conv<<<546, 256, 0, stream>>>(bsums, boffs, W[0], W[1], W[2], Wout,
                                       Wt0, Wt1, Wt2, Wto, colsum, Xv);
    scan3_kernel<<<NBLK, 256, 0, stream>>>(rowst, boffs, cursor);
    fill_kernel<<<(NE + 255) / 256, 256, 0, stream>>>(ei, cursor, csr);

    const ushort* hin = Xv;
    ushort* houts[3] = {hA, hB, hA};
    for (int li = 0; li < 3; ++li) {
        if (li == 0)
            gemm_mfma<IND><<<(NV + 63) / 64, 256, 0, stream>>>(hin, Wt[li], Asp[li], Adp[li], Hbuf, as_, ad_, vacc, vden);
        else
            gemm_mfma<HD><<<(NV + 63) / 64, 256, 0, stream>>>(hin, Wt[li], Asp[li], Adp[li], Hbuf, as_, ad_, vacc, vden);
        vsum_kernel<<<(NV + 63) / 64, 256, 0, stream>>>(as_, ad_, Hbuf, vden, vacc);
        node_kernel<<<NN / 4 + 1, 256, 0, stream>>>(rowst, csr, as_, ad_, Hbuf, vacc, vden,
                                                    Bb[li], Gg[li], Be[li], houts[li]);
        hin = houts[li];
    }
    out_mfma<<<(NN + 127) / 128, 256, 0, stream>>>(hin, Wto, bout, out);
}

// Round 9
// 457.954 us; speedup vs baseline: 2.4647x; 1.0501x over previous
//
#include <hip/hip_runtime.h>
#include <cmath>
#include <climits>

#define DEV __device__ __forceinline__

constexpr int NN  = 50000;    // real nodes
constexpr int NE  = 400000;   // regular edges
constexpr int NV  = NN + 1;   // + virtual node
constexpr int IND = 256;      // input dim
constexpr int HD  = 128;      // hidden dim
constexpr int NHC = 256;      // heads * hidden = GEMM N
constexpr int NBLK = (NN + 255) / 256;   // 196 scan blocks
constexpr int VB2  = (NN + 127) / 128;   // 391 vnode blocks (128 rows each)
constexpr int CB2  = (NE + 1023) / 1024; // 391 histogram blocks (4 edges/thread)

typedef short short8 __attribute__((ext_vector_type(8)));
typedef float f32x4  __attribute__((ext_vector_type(4)));

DEV float lrelu(float x) { return x > 0.f ? x : 0.2f * x; }
// tanh-form gelu (max abs err ~3e-4 vs exact erf form; well within tolerance)
DEV float gelu(float x) {
    float y = 0.7978845608028654f * (x + 0.044715f * x * x * x);
    float e = __expf(2.f * y);
    float t = (e - 1.f) * __frcp_rn(e + 1.f);   // tanh(y)
    return 0.5f * x * (1.f + t);
}
// bf16 storage as ushort; RNE convert
DEV ushort f2bf(float f) { uint u = __float_as_uint(f); return (ushort)((u + 0x7FFFu + ((u >> 16) & 1u)) >> 16); }
DEV float  bf2f(ushort h) { return __uint_as_float((uint)h << 16); }
// wave-uniform lane broadcast via v_readlane (no LDS pipe)
DEV float rlane_f(float v, int j) { return __uint_as_float(__builtin_amdgcn_readlane(__float_as_uint(v), j)); }

// ---------------- setup kernels ----------------

// fused: blocks [0,VB2): copy X -> Xv (bf16, float4/ushort4) + column sums;
//        blocks [VB2, VB2+CB2): edge dst histogram (int4)
__global__ __launch_bounds__(256) void vnode_count(const float* __restrict__ X,
                                                   ushort* __restrict__ Xv,
                                                   float* __restrict__ colsum,
                                                   const int* __restrict__ ei,
                                                   int* __restrict__ counts) {
    if (blockIdx.x < VB2) {
        __shared__ float cpart[4][256];
        int t = threadIdx.x;
        int w = t >> 6, l = t & 63;
        int r0 = blockIdx.x * 128 + w * 32;
        const float4* X4 = reinterpret_cast<const float4*>(X);
        ushort4*      Xv4 = reinterpret_cast<ushort4*>(Xv);
        float s0 = 0.f, s1 = 0.f, s2 = 0.f, s3 = 0.f;
        int rend = min(r0 + 32, NN);
        for (int r = r0; r < rend; ++r) {
            float4 v = X4[(size_t)r * 64 + l];
            ushort4 o = {f2bf(v.x), f2bf(v.y), f2bf(v.z), f2bf(v.w)};
            Xv4[(size_t)r * 64 + l] = o;
            s0 += v.x; s1 += v.y; s2 += v.z; s3 += v.w;
        }
        cpart[w][4 * l]     = s0;
        cpart[w][4 * l + 1] = s1;
        cpart[w][4 * l + 2] = s2;
        cpart[w][4 * l + 3] = s3;
        __syncthreads();
        float tot = cpart[0][t] + cpart[1][t] + cpart[2][t] + cpart[3][t];
        atomicAdd(&colsum[t], tot);
    } else {
        int e4 = (blockIdx.x - VB2) * 1024 + threadIdx.x * 4;
        if (e4 + 3 < NE) {
            int4 d = *reinterpret_cast<const int4*>(ei + NE + e4);
            atomicAdd(&counts[d.x], 1);
            atomicAdd(&counts[d.y], 1);
            atomicAdd(&counts[d.z], 1);
            atomicAdd(&counts[d.w], 1);
        } else {
            for (int j = e4; j < NE; ++j) atomicAdd(&counts[ei[NE + j]], 1);
        }
    }
}

// parallel scan, pass 1: per-block exclusive scan + block sums
__global__ __launch_bounds__(256) void scan1_kernel(const int* __restrict__ counts,
                                                    int* __restrict__ row_start,
                                                    int* __restrict__ blocksums) {
    __shared__ int s[256];
    int t = threadIdx.x, i = blockIdx.x * 256 + t;
    int v = (i < NN) ? counts[i] : 0;
    s[t] = v;
    __syncthreads();
    for (int off = 1; off < 256; off <<= 1) {
        int u = (t >= off) ? s[t - off] : 0;
        __syncthreads();
        s[t] += u;
        __syncthreads();
    }
    if (i < NN) row_start[i] = s[t] - v;      // local exclusive
    if (t == 255) blocksums[blockIdx.x] = s[255];
}

// pass 2 (block 0) + weight conversion (blocks 1..545)
__global__ __launch_bounds__(256) void scan2conv(const int* __restrict__ blocksums,
                                                 int* __restrict__ blockoffs,
                                                 const float* __restrict__ W0,
                                                 const float* __restrict__ W1,
                                                 const float* __restrict__ W2,
                                                 const float* __restrict__ Wout,
                                                 ushort* __restrict__ Wt0,
                                                 ushort* __restrict__ Wt1,
                                                 ushort* __restrict__ Wt2,
                                                 ushort* __restrict__ Wto,
                                                 const float* __restrict__ colsum,
                                                 ushort* __restrict__ Xv) {
    int t = threadIdx.x;
    if (blockIdx.x == 0) {
        __shared__ int s[256];
        int v = (t < NBLK) ? blocksums[t] : 0;
        s[t] = v;
        __syncthreads();
        for (int off = 1; off < 256; off <<= 1) {
            int u = (t >= off) ? s[t - off] : 0;
            __syncthreads();
            s[t] += u;
            __syncthreads();
        }
        if (t < NBLK) blockoffs[t] = s[t] - v;    // exclusive
        return;
    }
    int bid = blockIdx.x - 1;
    if (bid < 256) {               // W0: [256][256] -> Wt0 [256][256]
        int idx = bid * 256 + t;
        int k = idx >> 8, n = idx & 255;
        Wt0[n * IND + k] = f2bf(W0[idx]);
    } else if (bid < 384) {        // W1: [128][256] -> Wt1 [256][128]
        int idx = (bid - 256) * 256 + t;
        int k = idx >> 8, n = idx & 255;
        Wt1[n * HD + k] = f2bf(W1[idx]);
    } else if (bid < 512) {        // W2
        int idx = (bid - 384) * 256 + t;
        int k = idx >> 8, n = idx & 255;
        Wt2[n * HD + k] = f2bf(W2[idx]);
    } else if (bid < 544) {        // Wout: [128][64] -> Wto [64][128]
        int idx = (bid - 512) * 256 + t;
        int k = idx >> 6, n = idx & 63;
        Wto[n * HD + k] = f2bf(Wout[idx]);
    } else {                       // virtual node row
        Xv[(size_t)NN * IND + t] = f2bf(colsum[t] * (1.0f / NN));
    }
}

// pass 3: add block offsets, init cursor, set row_start[NN]
__global__ __launch_bounds__(256) void scan3_kernel(int* __restrict__ row_start,
                                                    const int* __restrict__ blockoffs,
                                                    int* __restrict__ cursor) {
    int i = blockIdx.x * 256 + threadIdx.x;
    if (i < NN) {
        int r = row_start[i] + blockoffs[blockIdx.x];
        row_start[i] = r;
        cursor[i]    = r;
    }
    if (i == 0) row_start[NN] = NE;
}

__global__ __launch_bounds__(256) void fill_kernel(const int* __restrict__ ei,
                                                   int* __restrict__ cursor,
                                                   int* __restrict__ csr) {
    int e = blockIdx.x * 256 + threadIdx.x;
    if (e < NE) {
        int d   = ei[NE + e];
        int pos = atomicAdd(&cursor[d], 1);
        csr[pos] = ei[e];
    }
}

// ---------------- per-layer kernels ----------------

// H[NV][256](bf16) = A[NV][K](bf16) @ Wt[256][K]^T(bf16), fp32 acc via MFMA.
// Whole B (or K-half for K=256) staged ONCE in 64KB LDS (XOR-swizzled,
// reg-staged ds_write); K-loop runs barrier-free. Block = 8 waves (4x2):
// 128 rows x 256 cols; wave = 32 rows x 128 cols. 16 waves/CU.
// Fused: alpha epilogue (wave wc covers head wc); block 0 zeroes vacc/vden.
template <int K>
__global__ __launch_bounds__(512, 4) void gemm_mfma(const ushort* __restrict__ A,
                                                    const ushort* __restrict__ Bt,
                                                    const float* __restrict__ a_s,
                                                    const float* __restrict__ a_d,
                                                    ushort* __restrict__ H,
                                                    float* __restrict__ as_,
                                                    float* __restrict__ ad_,
                                                    float* __restrict__ vacc,
                                                    float* __restrict__ vden) {
    __shared__ ushort Bs[256 * 128];           // 64KB: [col][128 k], chunk-swizzled
    if (blockIdx.x == 0) {                     // zero virtual-node accumulators
        if (threadIdx.x < 256) vacc[threadIdx.x] = 0.f;
        if (threadIdx.x < 2) vden[threadIdx.x] = 0.f;
    }
    const int tid  = threadIdx.x;
    const int wave = tid >> 6, lane = tid & 63;
    const int wr   = wave >> 1, wc = wave & 1;
    const int lrow = lane & 15, lk = lane >> 4;
    const int r0   = blockIdx.x * 128 + wr * 32;

    int ar0 = min(r0 + lrow,      NV - 1);
    int ar1 = min(r0 + 16 + lrow, NV - 1);
    const ushort* Ap0 = A + (size_t)ar0 * K + lk * 8;
    const ushort* Ap1 = A + (size_t)ar1 * K + lk * 8;

    f32x4 acc[2][8] = {};
#pragma unroll
    for (int h = 0; h < K / 128; ++h) {
        __syncthreads();                       // safe overwrite (no-op cost at h=0)
        // stage 64KB: 512 threads x 8 ushort8 chunks, swizzle chunk ^= col&7
#pragma unroll
        for (int i = 0; i < 8; ++i) {
            int chunkid = tid + i * 512;       // < 4096
            int col = chunkid >> 4, c = chunkid & 15;
            short8 v = *reinterpret_cast<const short8*>(Bt + (size_t)col * K + h * 128 + c * 8);
            *reinterpret_cast<short8*>(&Bs[col * 128 + ((c ^ (col & 7)) << 3)]) = v;
        }
        __syncthreads();
#pragma unroll
        for (int k0 = 0; k0 < 128; k0 += 32) {
            short8 a0 = *reinterpret_cast<const short8*>(Ap0 + h * 128 + k0);
            short8 a1 = *reinterpret_cast<const short8*>(Ap1 + h * 128 + k0);
#pragma unroll
            for (int n = 0; n < 8; ++n) {
                int col = wc * 128 + n * 16 + lrow;
                int c   = ((k0 >> 3) + lk) ^ (col & 7);
                short8 bf = *reinterpret_cast<const short8*>(&Bs[col * 128 + (c << 3)]);
                acc[0][n] = __builtin_amdgcn_mfma_f32_16x16x32_bf16(a0, bf, acc[0][n], 0, 0, 0);
                acc[1][n] = __builtin_amdgcn_mfma_f32_16x16x32_bf16(a1, bf, acc[1][n], 0, 0, 0);
            }
        }
    }

    // C/D layout: col = wc*128 + n*16 + lrow, row = r0 + m*16 + lk*4 + r
#pragma unroll
    for (int m = 0; m < 2; ++m)
#pragma unroll
        for (int n = 0; n < 8; ++n) {
            int c = wc * 128 + n * 16 + lrow;
#pragma unroll
            for (int r = 0; r < 4; ++r) {
                int row = r0 + m * 16 + lk * 4 + r;
                if (row < NV) H[(size_t)row * NHC + c] = f2bf(acc[m][n][r]);
            }
        }

    // fused alpha for head wc: coef flat index = wc*128 + col_within_head
    float cs[8], cd[8];
#pragma unroll
    for (int n = 0; n < 8; ++n) {
        cs[n] = a_s[wc * 128 + n * 16 + lrow];
        cd[n] = a_d[wc * 128 + n * 16 + lrow];
    }
#pragma unroll
    for (int m = 0; m < 2; ++m)
#pragma unroll
        for (int r = 0; r < 4; ++r) {
            float s = 0.f, d = 0.f;
#pragma unroll
            for (int n = 0; n < 8; ++n) {
                s += acc[m][n][r] * cs[n];
                d += acc[m][n][r] * cd[n];
            }
            for (int off = 1; off < 16; off <<= 1) {
                s += __shfl_xor(s, off);
                d += __shfl_xor(d, off);
            }
            int row = r0 + m * 16 + lk * 4 + r;
            if (lrow == 0 && row < NV) {
                as_[row * 2 + wc] = s;
                ad_[row * 2 + wc] = d;
            }
        }
}

// weighted sum over all NV rows into vacc[256], denom into vden[2].
// Vectorized: wave w handles 16 rows, lane covers 4 cols (ushort4 loads);
// cross-wave LDS reduce -> 256 atomics/block. No max subtraction (e bounded).
__global__ __launch_bounds__(256) void vsum_kernel(const float* __restrict__ as_,
                                                   const float* __restrict__ ad_,
                                                   const ushort* __restrict__ H,
                                                   float* __restrict__ vden,
                                                   float* __restrict__ vacc) {
    __shared__ float w0s[64], w1s[64];
    __shared__ float part[4][256];
    int t = threadIdx.x;
    int w = t >> 6, l = t & 63;
    int r0 = blockIdx.x * 64;
    if (t < 64) {
        int r = r0 + t;
        float p0 = 0.f, p1 = 0.f;
        if (r < NV) {
            float2 adv = *reinterpret_cast<const float2*>(ad_ + 2 * NN);
            float2 asv = *reinterpret_cast<const float2*>(as_ + 2 * r);
            p0 = __expf(lrelu(asv.x + adv.x));
            p1 = __expf(lrelu(asv.y + adv.y));
        }
        w0s[t] = p0; w1s[t] = p1;
    }
    __syncthreads();
    const ushort4* H4 = reinterpret_cast<const ushort4*>(H);
    bool h0 = l < 32;
    float a0 = 0.f, a1 = 0.f, a2 = 0.f, a3 = 0.f;
    int rbase = r0 + w * 16;
#pragma unroll 4
    for (int it = 0; it < 16; ++it) {
        int r = rbase + it;
        if (r < NV) {
            float wt = h0 ? w0s[w * 16 + it] : w1s[w * 16 + it];
            ushort4 q = H4[(size_t)r * 64 + l];
            a0 += wt * bf2f(q.x); a1 += wt * bf2f(q.y);
            a2 += wt * bf2f(q.z); a3 += wt * bf2f(q.w);
        }
    }
    part[w][4 * l]     = a0;
    part[w][4 * l + 1] = a1;
    part[w][4 * l + 2] = a2;
    part[w][4 * l + 3] = a3;
    __syncthreads();
    float tot = part[0][t] + part[1][t] + part[2][t] + part[3][t];
    atomicAdd(&vacc[t], tot);
    if (t < 2) {
        const float* ws = t ? w1s : w0s;
        float d = 0.f;
        for (int j = 0; j < 64; ++j) d += ws[j];
        atomicAdd(&vden[t], d);
    }
}

// regular nodes: one wave per dst node. Unnormalized Σ p·H[src]; per-lane
// weight precompute, v_readlane broadcast (j is wave-uniform), 4-wide
// unrolled gathers for MLP. Lane covers 4 cols of one head (ushort4);
// head-mean via shfl_xor(32). Virtual node (i==NN) reads vacc/vden.
// LN + gelu fused.
__global__ __launch_bounds__(256) void node_kernel(const int* __restrict__ row_start,
                                                   const int* __restrict__ csr,
                                                   const float* __restrict__ as_,
                                                   const float* __restrict__ ad_,
                                                   const ushort* __restrict__ H,
                                                   const float* __restrict__ vacc,
                                                   const float* __restrict__ vden,
                                                   const float* __restrict__ b,
                                                   const float* __restrict__ g,
                                                   const float* __restrict__ be,
                                                   ushort* __restrict__ hn) {
    int wave = threadIdx.x >> 6, lane = threadIdx.x & 63;
    int i = blockIdx.x * 4 + wave;
    if (i > NN) return;
    int  l5 = lane & 31;
    bool h0 = lane < 32;

    float acc0 = 0.f, acc1 = 0.f, acc2 = 0.f, acc3 = 0.f, dp;
    if (i == NN) {
        int base = (h0 ? 0 : 128) + 4 * l5;
        acc0 = vacc[base];     acc1 = vacc[base + 1];
        acc2 = vacc[base + 2]; acc3 = vacc[base + 3];
        dp = vden[h0 ? 0 : 1];
    } else {
        int rs = row_start[i], cnt = row_start[i + 1] - rs;
        int tot = cnt + 2; // + virtual, + self
        float2 adv = *reinterpret_cast<const float2*>(ad_ + 2 * i);
        float dp0 = 0.f, dp1 = 0.f;
        const ushort4* H4 = reinterpret_cast<const ushort4*>(H);
        for (int bse = 0; bse < tot; bse += 64) {
            int idx = bse + lane;
            int src_l = 0; float p0_l = 0.f, p1_l = 0.f;
            if (idx < tot) {
                src_l = idx < cnt ? csr[rs + idx] : (idx == cnt ? NN : i);
                float2 asv = *reinterpret_cast<const float2*>(as_ + 2 * src_l);
                p0_l = __expf(lrelu(asv.x + adv.x));
                p1_l = __expf(lrelu(asv.y + adv.y));
                dp0 += p0_l; dp1 += p1_l;
            }
            int chunk = min(64, tot - bse);
            int j = 0;
            for (; j + 4 <= chunk; j += 4) {
                int sA = __builtin_amdgcn_readlane(src_l, j);
                int sB = __builtin_amdgcn_readlane(src_l, j + 1);
                int sC = __builtin_amdgcn_readlane(src_l, j + 2);
                int sD = __builtin_amdgcn_readlane(src_l, j + 3);
                ushort4 qA = H4[(size_t)sA * 64 + lane];
                ushort4 qB = H4[(size_t)sB * 64 + lane];
                ushort4 qC = H4[(size_t)sC * 64 + lane];
                ushort4 qD = H4[(size_t)sD * 64 + lane];
                float wA = h0 ? rlane_f(p0_l, j)     : rlane_f(p1_l, j);
                float wB = h0 ? rlane_f(p0_l, j + 1) : rlane_f(p1_l, j + 1);
                float wC = h0 ? rlane_f(p0_l, j + 2) : rlane_f(p1_l, j + 2);
                float wD = h0 ? rlane_f(p0_l, j + 3) : rlane_f(p1_l, j + 3);
                acc0 += wA * bf2f(qA.x); acc1 += wA * bf2f(qA.y);
                acc2 += wA * bf2f(qA.z); acc3 += wA * bf2f(qA.w);
                acc0 += wB * bf2f(qB.x); acc1 += wB * bf2f(qB.y);
                acc2 += wB * bf2f(qB.z); acc3 += wB * bf2f(qB.w);
                acc0 += wC * bf2f(qC.x); acc1 += wC * bf2f(qC.y);
                acc2 += wC * bf2f(qC.z); acc3 += wC * bf2f(qC.w);
                acc0 += wD * bf2f(qD.x); acc1 += wD * bf2f(qD.y);
                acc2 += wD * bf2f(qD.z); acc3 += wD * bf2f(qD.w);
            }
            for (; j < chunk; ++j) {
                int   s = __builtin_amdgcn_readlane(src_l, j);
                ushort4 q = H4[(size_t)s * 64 + lane];
                float w = h0 ? rlane_f(p0_l, j) : rlane_f(p1_l, j);
                acc0 += w * bf2f(q.x); acc1 += w * bf2f(q.y);
                acc2 += w * bf2f(q.z); acc3 += w * bf2f(q.w);
            }
        }
        for (int off = 32; off; off >>= 1) {
            dp0 += __shfl_xor(dp0, off);
            dp1 += __shfl_xor(dp1, off);
        }
        dp = h0 ? dp0 : dp1;
    }

    float r = 1.f / (dp + 1e-16f);
    float4 bv = reinterpret_cast<const float4*>(b)[l5];
    float z0 = acc0 * r, z1 = acc1 * r, z2 = acc2 * r, z3 = acc3 * r;
    float y0 = 0.5f * (z0 + __shfl_xor(z0, 32)) + bv.x;
    float y1 = 0.5f * (z1 + __shfl_xor(z1, 32)) + bv.y;
    float y2 = 0.5f * (z2 + __shfl_xor(z2, 32)) + bv.z;
    float y3 = 0.5f * (z3 + __shfl_xor(z3, 32)) + bv.w;
    // LN over 128 dims; each dim appears twice across the wave -> /256
    float s = y0 + y1 + y2 + y3;
    for (int off = 32; off; off >>= 1) s += __shfl_xor(s, off);
    float mu = s * (1.f / 256.f);
    float c0 = y0 - mu, c1 = y1 - mu, c2 = y2 - mu, c3 = y3 - mu;
    float v = c0 * c0 + c1 * c1 + c2 * c2 + c3 * c3;
    for (int off = 32; off; off >>= 1) v += __shfl_xor(v, off);
    float rstd = rsqrtf(v * (1.f / 256.f) + 1e-5f);
    if (h0) {
        float4 gv  = reinterpret_cast<const float4*>(g)[l5];
        float4 bev = reinterpret_cast<const float4*>(be)[l5];
        ushort4 o;
        o.x = f2bf(gelu(c0 * rstd * gv.x + bev.x));
        o.y = f2bf(gelu(c1 * rstd * gv.y + bev.y));
        o.z = f2bf(gelu(c2 * rstd * gv.z + bev.z));
        o.w = f2bf(gelu(c3 * rstd * gv.w + bev.w));
        *reinterpret_cast<ushort4*>(&hn[(size_t)i * HD + 4 * l5]) = o;
    }
}

// out[NN][64] = h[NN][128](bf16) @ Wto[64][128]^T(bf16) + bout, via MFMA.
// Whole Wto (16KB) staged once (swizzled); barrier-free K-loop.
__global__ __launch_bounds__(256) void out_mfma(const ushort* __restrict__ A,
                                                const ushort* __restrict__ Bt,
                                                const float* __restrict__ bout,
                                                float* __restrict__ out) {
    __shared__ ushort Bs[64 * 128];            // 16KB, chunk-swizzled
    const int tid  = threadIdx.x;
    const int wave = tid >> 6, lane = tid & 63;
    const int lrow = lane & 15, lk = lane >> 4;
    const int r0   = blockIdx.x * 128 + wave * 32;

    // stage: 1024 chunks of 16B, 256 threads x 4
#pragma unroll
    for (int i = 0; i < 4; ++i) {
        int chunkid = tid + i * 256;
        int col = chunkid >> 4, c = chunkid & 15;
        short8 v = *reinterpret_cast<const short8*>(Bt + (size_t)col * HD + c * 8);
        *reinterpret_cast<short8*>(&Bs[col * 128 + ((c ^ (col & 7)) << 3)]) = v;
    }
    __syncthreads();

    int ar0 = min(r0 + lrow,      NN - 1);
    int ar1 = min(r0 + 16 + lrow, NN - 1);
    const ushort* Ap0 = A + (size_t)ar0 * HD + lk * 8;
    const ushort* Ap1 = A + (size_t)ar1 * HD + lk * 8;

    f32x4 acc[2][4] = {};
#pragma unroll
    for (int k0 = 0; k0 < HD; k0 += 32) {
        short8 a0 = *reinterpret_cast<const short8*>(Ap0 + k0);
        short8 a1 = *reinterpret_cast<const short8*>(Ap1 + k0);
#pragma unroll
        for (int n = 0; n < 4; ++n) {
            int col = n * 16 + lrow;
            int c   = ((k0 >> 3) + lk) ^ (col & 7);
            short8 bf = *reinterpret_cast<const short8*>(&Bs[col * 128 + (c << 3)]);
            acc[0][n] = __builtin_amdgcn_mfma_f32_16x16x32_bf16(a0, bf, acc[0][n], 0, 0, 0);
            acc[1][n] = __builtin_amdgcn_mfma_f32_16x16x32_bf16(a1, bf, acc[1][n], 0, 0, 0);
        }
    }
#pragma unroll
    for (int m = 0; m < 2; ++m)
#pragma unroll
        for (int n = 0; n < 4; ++n) {
            int c = n * 16 + lrow;
            float bc = bout[c];
#pragma unroll
            for (int r = 0; r < 4; ++r) {
                int row = r0 + m * 16 + lk * 4 + r;
                if (row < NN) out[(size_t)row * 64 + c] = acc[m][n][r] + bc;
            }
        }
}

// ---------------- launcher ----------------

extern "C" void kernel_launch(void* const* d_in, const int* in_sizes, int n_in,
                              void* d_out, int out_size, void* d_ws, size_t ws_size,
                              hipStream_t stream) {
    (void)in_sizes; (void)n_in; (void)out_size; (void)ws_size;

    const float* X  = (const float*)d_in[0];
    const int*   ei = (const int*)d_in[1];
    const float* W[3]   = {(const float*)d_in[3],  (const float*)d_in[9],  (const float*)d_in[15]};
    const float* Asp[3] = {(const float*)d_in[4],  (const float*)d_in[10], (const float*)d_in[16]};
    const float* Adp[3] = {(const float*)d_in[5],  (const float*)d_in[11], (const float*)d_in[17]};
    const float* Bb[3]  = {(const float*)d_in[6],  (const float*)d_in[12], (const float*)d_in[18]};
    const float* Gg[3]  = {(const float*)d_in[7],  (const float*)d_in[13], (const float*)d_in[19]};
    const float* Be[3]  = {(const float*)d_in[8],  (const float*)d_in[14], (const float*)d_in[20]};
    const float* Wout = (const float*)d_in[21];
    const float* bout = (const float*)d_in[22];
    float* out = (float*)d_out;

    uintptr_t base = (uintptr_t)d_ws;
    auto take = [&](size_t bytes) {
        uintptr_t p = base;
        base += (bytes + 255) & ~(size_t)255;
        return p;
    };
    ushort* Xv    = (ushort*)take((size_t)NV * IND * 2);
    ushort* Hbuf  = (ushort*)take((size_t)NV * NHC * 2);
    ushort* hA    = (ushort*)take((size_t)NV * HD * 2);
    ushort* hB    = (ushort*)take((size_t)NV * HD * 2);
    ushort* Wt0   = (ushort*)take((size_t)256 * IND * 2);
    ushort* Wt1   = (ushort*)take((size_t)256 * HD * 2);
    ushort* Wt2   = (ushort*)take((size_t)256 * HD * 2);
    ushort* Wto   = (ushort*)take((size_t)64 * HD * 2);
    float* as_    = (float*)take((size_t)NV * 2 * 4);
    float* ad_    = (float*)take((size_t)NV * 2 * 4);
    float* colsum = (float*)take(256 * 4);
    int*   counts = (int*)take((size_t)NN * 4);
    int*   rowst  = (int*)take((size_t)(NN + 1) * 4);
    int*   cursor = (int*)take((size_t)NN * 4);
    int*   csr    = (int*)take((size_t)NE * 4);
    int*   bsums  = (int*)take((size_t)NBLK * 4);
    int*   boffs  = (int*)take((size_t)NBLK * 4);
    float* vden   = (float*)take(2 * 4);
    float* vacc   = (float*)take(256 * 4);
    ushort* Wt[3] = {Wt0, Wt1, Wt2};

    // setup: zero counts + colsum via memset (graph-capturable)
    hipMemsetAsync(counts, 0, (size_t)NN * 4, stream);
    hipMemsetAsync(colsum, 0, 256 * 4, stream);
    vnode_count<<<VB2 + CB2, 256, 0, stream>>>(X, Xv, colsum, ei, counts);
    scan1_kernel<<<NBLK, 256, 0, stream>>>(counts, rowst, bsums);
    scan2conv<<<546, 256, 0, stream>>>(bsums, boffs, W[0], W[1], W[2], Wout,
                                       Wt0, Wt1, Wt2, Wto, colsum, Xv);
    scan3_kernel<<<NBLK, 256, 0, stream>>>(rowst, boffs, cursor);
    fill_kernel<<<(NE + 255) / 256, 256, 0, stream>>>(ei, cursor, csr);

    const ushort* hin = Xv;
    ushort* houts[3] = {hA, hB, hA};
    for (int li = 0; li < 3; ++li) {
        if (li == 0)
            gemm_mfma<IND><<<(NV + 127) / 128, 512, 0, stream>>>(hin, Wt[li], Asp[li], Adp[li], Hbuf, as_, ad_, vacc, vden);
        else
            gemm_mfma<HD><<<(NV + 127) / 128, 512, 0, stream>>>(hin, Wt[li], Asp[li], Adp[li], Hbuf, as_, ad_, vacc, vden);
        vsum_kernel<<<(NV + 63) / 64, 256, 0, stream>>>(as_, ad_, Hbuf, vden, vacc);
        node_kernel<<<NN / 4 + 1, 256, 0, stream>>>(rowst, csr, as_, ad_, Hbuf, vacc, vden,
                                                    Bb[li], Gg[li], Be[li], houts[li]);
        hin = houts[li];
    }
    out_mfma<<<(NN + 127) / 128, 256, 0, stream>>>(hin, Wto, bout, out);
}